// Round 9
// baseline (2554.161 us; speedup 1.0000x reference)
//
#include <hip/hip_runtime.h>
#include <hip/hip_bf16.h>
#include <math.h>

#define N_NODES 8192
#define D_DLG   64
#define L_SEQ   128
#define H_DIM   512
#define N_HEADS 8
#define DHEAD   64
#define FF_DIM  2048
#define E_EDGES 32768

typedef __hip_bfloat16 bf16;
typedef __attribute__((ext_vector_type(8))) short short8;
typedef __attribute__((ext_vector_type(4))) float f32x4;

// ---------------- load/store helpers (bf16 <-> f32) -------------------------
__device__ __forceinline__ float bconv(unsigned short u) {
    return __uint_as_float((unsigned)u << 16);
}
__device__ __forceinline__ unsigned short fconv(float f) {
    bf16 h = __float2bfloat16(f);
    return *(unsigned short*)&h;
}
__device__ __forceinline__ float4 ld4(const float* p) { return *(const float4*)p; }
__device__ __forceinline__ float4 ld4(const bf16* p) {
    ushort4 u = *(const ushort4*)p;
    float4 v;
    v.x = bconv(u.x); v.y = bconv(u.y); v.z = bconv(u.z); v.w = bconv(u.w);
    return v;
}
__device__ __forceinline__ float ld1(const float* p) { return *p; }
__device__ __forceinline__ float ld1(const bf16* p) { return bconv(*(const unsigned short*)p); }
__device__ __forceinline__ void st1(float* p, float v) { *p = v; }
__device__ __forceinline__ void st1(bf16* p, float v) { *p = __float2bfloat16(v); }

__device__ __forceinline__ void gld_lds16(const bf16* g, bf16* l) {
    __builtin_amdgcn_global_load_lds(
        (const __attribute__((address_space(1))) void*)g,
        (__attribute__((address_space(3))) void*)l, 16, 0, 0);
}

// ---------------------------------------------------------------------------
// Weight pre-pass: f32 [z][K][N] -> bf16 [z][N][K] (transpose + convert).
// ---------------------------------------------------------------------------
__global__ __launch_bounds__(256) void transpose_k(const float* __restrict__ in,
                                                   bf16* __restrict__ out, int K, int N)
{
    __shared__ float tile[32][33];
    const long zoff = (long)blockIdx.z * K * N;
    const int n0 = blockIdx.x * 32, k0 = blockIdx.y * 32;
    const int tx = threadIdx.x, ty = threadIdx.y;
#pragma unroll
    for (int i = 0; i < 4; ++i)
        tile[ty + i * 8][tx] = in[zoff + (long)(k0 + ty + i * 8) * N + n0 + tx];
    __syncthreads();
#pragma unroll
    for (int i = 0; i < 4; ++i)
        st1(out + zoff + (long)(n0 + ty + i * 8) * K + k0 + tx, tile[tx][ty + i * 8]);
}

// ---------------------------------------------------------------------------
// MFMA GEMM: C = act(A @ Bt^T + bias). A bf16 [M][K] (lda), Bt bf16 [N][K]
// (ldb), C row-major (ldc). 64x64 tile, BK=32, 4 waves (2x2, 32x32 each).
// Both-sides XOR bank-swizzle + bijective XCD tile swizzle. Strides sA/sB/
// sC/sBias per blockIdx.z allow z-batched projections AND split-K (z over
// K-chunks writing disjoint f32 partial buffers). (R5-passing kernel.)
// ---------------------------------------------------------------------------
template <typename TC>
__global__ __launch_bounds__(256) void mgemm_k(
    const bf16* __restrict__ A, const bf16* __restrict__ Bt,
    const float* __restrict__ bias, TC* __restrict__ C,
    int M, int K, int Ncols, int lda, int ldb, int ldc,
    long sA, long sB, long sC, long sBias, int act)
{
    A  += (long)blockIdx.z * sA;
    Bt += (long)blockIdx.z * sB;
    C  += (long)blockIdx.z * sC;
    const float* bp = bias ? bias + (long)blockIdx.z * sBias : nullptr;

    __shared__ bf16 As[2][64 * 32];
    __shared__ bf16 Bs[2][64 * 32];

    const int tid  = threadIdx.x;
    const int lane = tid & 63;
    const int wave = tid >> 6;
    const int wr   = wave >> 1;
    const int wc   = wave & 1;

    // ---- XCD-aware bijective tile swizzle (all launches have nwg % 8 == 0) -
    const int nwgx = gridDim.x;
    const int nwg  = nwgx * gridDim.y;
    int orig = blockIdx.y * nwgx + blockIdx.x;
    int wgid = ((nwg & 7) == 0) ? ((orig & 7) * (nwg >> 3) + (orig >> 3)) : orig;
    const int rowTile = (wgid / nwgx) * 64;
    const int colTile = (wgid % nwgx) * 64;

    // ---- staging: wave w covers rows w*16..w*16+15; lane l -> row w*16+(l>>2),
    //      LDS k-chunk (l&3); global source chunk carries the inverse XOR ----
    const int ar  = wave * 16 + (lane >> 2);
    const int aks = (((lane & 3) ^ ((lane >> 3) & 3)) * 8);

    // ---- fragment read: slot (kgrp ^ ((frow>>1)&3)) holds chunk kgrp -------
    const int frow = lane & 15;
    const int kgrp = lane >> 4;
    const int slot = (kgrp ^ ((frow >> 1) & 3)) * 8;

    f32x4 acc[2][2];
#pragma unroll
    for (int i = 0; i < 2; ++i)
#pragma unroll
        for (int j = 0; j < 2; ++j) acc[i][j] = (f32x4){0.f, 0.f, 0.f, 0.f};

    const int nk = K >> 5;

#define STAGE(buf, kk)                                                          \
    do {                                                                        \
        gld_lds16(A  + (long)(rowTile + ar) * lda + (kk) + aks, &As[buf][wave * 512]); \
        gld_lds16(Bt + (long)(colTile + ar) * ldb + (kk) + aks, &Bs[buf][wave * 512]); \
    } while (0)

    auto compute = [&](const bf16* as, const bf16* bs) {
        short8 av[2], bv[2];
#pragma unroll
        for (int mi = 0; mi < 2; ++mi)
            av[mi] = *(const short8*)(as + (wr * 32 + mi * 16 + frow) * 32 + slot);
#pragma unroll
        for (int ni = 0; ni < 2; ++ni)
            bv[ni] = *(const short8*)(bs + (wc * 32 + ni * 16 + frow) * 32 + slot);
#pragma unroll
        for (int mi = 0; mi < 2; ++mi)
#pragma unroll
            for (int ni = 0; ni < 2; ++ni)
                acc[mi][ni] = __builtin_amdgcn_mfma_f32_16x16x32_bf16(
                    av[mi], bv[ni], acc[mi][ni], 0, 0, 0);
    };

    STAGE(0, 0);
    __syncthreads();

    for (int t = 0; t < nk; t += 2) {
        if (t + 1 < nk) STAGE(1, (t + 1) * 32);
        compute(As[0], Bs[0]);
        __syncthreads();
        if (t + 1 < nk) {
            if (t + 2 < nk) STAGE(0, (t + 2) * 32);
            compute(As[1], Bs[1]);
            __syncthreads();
        }
    }
#undef STAGE

#pragma unroll
    for (int ni = 0; ni < 2; ++ni) {
        int col = colTile + wc * 32 + ni * 16 + frow;
        if (col < Ncols) {
            float bb = bp ? bp[col] : 0.f;
#pragma unroll
            for (int mi = 0; mi < 2; ++mi) {
                long rbase = rowTile + wr * 32 + mi * 16 + kgrp * 4;
#pragma unroll
                for (int r = 0; r < 4; ++r) {
                    float v = acc[mi][ni][r] + bb;
                    if (act == 1) v = fmaxf(v, 0.f);
                    st1(C + (rbase + r) * (long)ldc + col, v);
                }
            }
        }
    }
}

// ---------------------------------------------------------------------------
// MFMA flash attention per (dialogue, head). 256 thr = 4 waves.
// ---------------------------------------------------------------------------
__global__ __launch_bounds__(256) void attn_mfma_k(const bf16* __restrict__ qkv,
                                                   bf16* __restrict__ o)
{
    __shared__ bf16 Pb[128 * 136];   // 34.8 KB, A-layout P
    __shared__ bf16 Vt[64 * 136];    // 17.4 KB, V^T [dh][l]
    __shared__ float pm[128][2];     // per-row partial max (per wave-col)
    __shared__ float ps[128][2];     // per-row partial sum

    const int d = blockIdx.x, h = blockIdx.y;
    const long base = (long)d * L_SEQ;
    const int tid  = threadIdx.x;
    const int lane = tid & 63;
    const int wave = tid >> 6;
    const int frow = lane & 15;
    const int kgrp = lane >> 4;
    const int wr = wave >> 1;        // S row-half
    const int wc = wave & 1;         // S col-half
    const float SC = 0.125f;

    // ---- V[l][dh] -> Vt[dh][l] (one-time scalar transpose) -----------------
    {
        int l = tid >> 1, dh0 = (tid & 1) * 32;
        const bf16* vp = qkv + (base + l) * 1536 + 1024 + h * 64 + dh0;
        unsigned short* vt = (unsigned short*)Vt;
#pragma unroll
        for (int j = 0; j < 4; ++j) {
            short8 v = *(const short8*)(vp + j * 8);
#pragma unroll
            for (int jj = 0; jj < 8; ++jj)
                vt[(dh0 + j * 8 + jj) * 136 + l] = (unsigned short)v[jj];
        }
    }

    // ---- Q,K fragments direct from global (no reuse -> no LDS) -------------
    short8 aq[4][2], bk[4][2];
#pragma unroll
    for (int mi = 0; mi < 4; ++mi) {
        long row = base + wr * 64 + mi * 16 + frow;
#pragma unroll
        for (int ks = 0; ks < 2; ++ks)
            aq[mi][ks] = *(const short8*)(qkv + row * 1536 + h * 64 + ks * 32 + kgrp * 8);
    }
#pragma unroll
    for (int ni = 0; ni < 4; ++ni) {
        long row = base + wc * 64 + ni * 16 + frow;
#pragma unroll
        for (int ks = 0; ks < 2; ++ks)
            bk[ni][ks] = *(const short8*)(qkv + row * 1536 + 512 + h * 64 + ks * 32 + kgrp * 8);
    }

    // ---- S = Q @ K^T (64x64 per wave) --------------------------------------
    f32x4 acc[4][4];
#pragma unroll
    for (int i = 0; i < 4; ++i)
#pragma unroll
        for (int j = 0; j < 4; ++j) acc[i][j] = (f32x4){0.f, 0.f, 0.f, 0.f};
#pragma unroll
    for (int ks = 0; ks < 2; ++ks)
#pragma unroll
        for (int mi = 0; mi < 4; ++mi)
#pragma unroll
            for (int ni = 0; ni < 4; ++ni)
                acc[mi][ni] = __builtin_amdgcn_mfma_f32_16x16x32_bf16(
                    aq[mi][ks], bk[ni][ks], acc[mi][ni], 0, 0, 0);

    // ---- per-wave row partials ---------------------------------------------
#pragma unroll
    for (int mi = 0; mi < 4; ++mi) {
#pragma unroll
        for (int r = 0; r < 4; ++r) {
            float mv = -1e30f;
#pragma unroll
            for (int ni = 0; ni < 4; ++ni) mv = fmaxf(mv, acc[mi][ni][r] * SC);
#pragma unroll
            for (int off = 1; off < 16; off <<= 1)
                mv = fmaxf(mv, __shfl_xor(mv, off, 64));
            float sv = 0.f;
#pragma unroll
            for (int ni = 0; ni < 4; ++ni) sv += __expf(acc[mi][ni][r] * SC - mv);
#pragma unroll
            for (int off = 1; off < 16; off <<= 1)
                sv += __shfl_xor(sv, off, 64);
            if (frow == 0) {
                int row = wr * 64 + mi * 16 + kgrp * 4 + r;
                pm[row][wc] = mv;
                ps[row][wc] = sv;
            }
        }
    }
    __syncthreads();

    // ---- merge halves, write P (bf16, A-layout) ----------------------------
    unsigned short* pb = (unsigned short*)Pb;
#pragma unroll
    for (int mi = 0; mi < 4; ++mi) {
#pragma unroll
        for (int r = 0; r < 4; ++r) {
            int row = wr * 64 + mi * 16 + kgrp * 4 + r;
            float m0 = pm[row][0], m1 = pm[row][1];
            float M = fmaxf(m0, m1);
            float Ssum = ps[row][0] * __expf(m0 - M) + ps[row][1] * __expf(m1 - M);
            float inv = 1.f / Ssum;
#pragma unroll
            for (int ni = 0; ni < 4; ++ni) {
                int col = wc * 64 + ni * 16 + frow;
                float p = __expf(acc[mi][ni][r] * SC - M) * inv;
                pb[row * 136 + col] = fconv(p);
            }
        }
    }
    __syncthreads();

    // ---- O = P @ V ----------------------------------------------------------
    f32x4 acc2[2][4];
#pragma unroll
    for (int i = 0; i < 2; ++i)
#pragma unroll
        for (int j = 0; j < 4; ++j) acc2[i][j] = (f32x4){0.f, 0.f, 0.f, 0.f};
#pragma unroll
    for (int ks = 0; ks < 4; ++ks) {
        short8 ap[2], bv[4];
#pragma unroll
        for (int mi = 0; mi < 2; ++mi)
            ap[mi] = *(const short8*)(Pb + (wave * 32 + mi * 16 + frow) * 136 + ks * 32 + kgrp * 8);
#pragma unroll
        for (int ni = 0; ni < 4; ++ni)
            bv[ni] = *(const short8*)(Vt + (ni * 16 + frow) * 136 + ks * 32 + kgrp * 8);
#pragma unroll
        for (int mi = 0; mi < 2; ++mi)
#pragma unroll
            for (int ni = 0; ni < 4; ++ni)
                acc2[mi][ni] = __builtin_amdgcn_mfma_f32_16x16x32_bf16(
                    ap[mi], bv[ni], acc2[mi][ni], 0, 0, 0);
    }
#pragma unroll
    for (int mi = 0; mi < 2; ++mi) {
#pragma unroll
        for (int ni = 0; ni < 4; ++ni) {
            int col = ni * 16 + frow;
            long rowb = wave * 32 + mi * 16 + kgrp * 4;
#pragma unroll
            for (int r = 0; r < 4; ++r)
                st1(o + (base + rowb + r) * 512 + h * 64 + col, acc2[mi][ni][r]);
        }
    }
}

// ---------------------------------------------------------------------------
// Classifier head: out[N,7] = A[N,768] @ W[768,7] + bias. Wave per row.
// ---------------------------------------------------------------------------
__global__ __launch_bounds__(256) void head7_k(
    const bf16* __restrict__ A, const float* __restrict__ W,
    const float* __restrict__ bias, float* __restrict__ out)
{
    const int wave = threadIdx.x >> 6, lane = threadIdx.x & 63;
    const long row = blockIdx.x * 4 + wave;
    const bf16* a = A + row * 768;
    float acc[7];
#pragma unroll
    for (int j = 0; j < 7; ++j) acc[j] = 0.f;
#pragma unroll
    for (int i = 0; i < 12; ++i) {
        int k = lane + i * 64;
        float av = ld1(a + k);
        const float* w = W + k * 7;
#pragma unroll
        for (int j = 0; j < 7; ++j) acc[j] = fmaf(av, w[j], acc[j]);
    }
#pragma unroll
    for (int j = 0; j < 7; ++j)
#pragma unroll
        for (int o = 32; o > 0; o >>= 1) acc[j] += __shfl_down(acc[j], o, 64);
    if (lane == 0) {
#pragma unroll
        for (int j = 0; j < 7; ++j) out[row * 7 + j] = acc[j] + bias[j];
    }
}

// ---------------------------------------------------------------------------
// xcat: vectorized x4 (4-aligned quads never straddle source regions).
// ---------------------------------------------------------------------------
__global__ void xcat_k(const float* __restrict__ x, const float* __restrict__ spk_emb,
                       const int* __restrict__ sidx, bf16* __restrict__ out, int n_quads)
{
    int q = blockIdx.x * 256 + threadIdx.x;
    if (q >= n_quads) return;
    int i = q * 4;
    int n = i / 576;
    int c = i - n * 576;
    const float* sp = (c < 512) ? (x + (long)n * 512 + c)
                                : (spk_emb + (long)sidx[n] * 64 + (c - 512));
    float4 v = *(const float4*)sp;
    ushort4 u;
    u.x = fconv(v.x); u.y = fconv(v.y); u.z = fconv(v.z); u.w = fconv(v.w);
    *(ushort4*)(out + i) = u;
}

// ---------------------------------------------------------------------------
// add_ln: pair-loads; residual r is bf16.
// ---------------------------------------------------------------------------
__global__ __launch_bounds__(256) void add_ln_k(bf16* __restrict__ h, const bf16* __restrict__ r,
                                                const float* __restrict__ g, const float* __restrict__ b)
{
    const int row = blockIdx.x;
    const int tid = threadIdx.x;
    const long base = (long)row * 512 + tid * 2;
    ushort2 hu = *(const ushort2*)(h + base);
    ushort2 ru = *(const ushort2*)(r + base);
    float x0 = bconv(hu.x) + bconv(ru.x);
    float x1 = bconv(hu.y) + bconv(ru.y);
    float s = x0 + x1;
    float q = x0 * x0 + x1 * x1;
#pragma unroll
    for (int o = 32; o > 0; o >>= 1) { s += __shfl_down(s, o, 64); q += __shfl_down(q, o, 64); }
    __shared__ float ls[4], lq[4];
    if ((tid & 63) == 0) { ls[tid >> 6] = s; lq[tid >> 6] = q; }
    __syncthreads();
    float S = ls[0] + ls[1] + ls[2] + ls[3];
    float Q = lq[0] + lq[1] + lq[2] + lq[3];
    float mu = S * (1.f / 512.f);
    float var = Q * (1.f / 512.f) - mu * mu;
    float inv = rsqrtf(fmaxf(var, 0.f) + 1e-5f);
    float2 gv = *(const float2*)(g + tid * 2);
    float2 bv = *(const float2*)(b + tid * 2);
    ushort2 o2;
    o2.x = fconv((x0 - mu) * inv * gv.x + bv.x);
    o2.y = fconv((x1 - mu) * inv * gv.y + bv.y);
    *(ushort2*)(h + base) = o2;
}

// ---------------------------------------------------------------------------
// add_ln2: residual = c0 + c1 + bias (split-K f32 partials); h = LN(h + res).
// ---------------------------------------------------------------------------
__global__ __launch_bounds__(256) void add_ln2_k(
    bf16* __restrict__ h, const float* __restrict__ c0, const float* __restrict__ c1,
    const float* __restrict__ bias, const float* __restrict__ g, const float* __restrict__ b)
{
    const int row = blockIdx.x;
    const int tid = threadIdx.x;
    const long base = (long)row * 512 + tid * 2;
    ushort2 hu = *(const ushort2*)(h + base);
    float2 a0 = *(const float2*)(c0 + base);
    float2 a1 = *(const float2*)(c1 + base);
    float2 bb = *(const float2*)(bias + tid * 2);
    float x0 = bconv(hu.x) + (a0.x + a1.x + bb.x);
    float x1 = bconv(hu.y) + (a0.y + a1.y + bb.y);
    float s = x0 + x1;
    float q = x0 * x0 + x1 * x1;
#pragma unroll
    for (int o = 32; o > 0; o >>= 1) { s += __shfl_down(s, o, 64); q += __shfl_down(q, o, 64); }
    __shared__ float ls[4], lq[4];
    if ((tid & 63) == 0) { ls[tid >> 6] = s; lq[tid >> 6] = q; }
    __syncthreads();
    float S = ls[0] + ls[1] + ls[2] + ls[3];
    float Q = lq[0] + lq[1] + lq[2] + lq[3];
    float mu = S * (1.f / 512.f);
    float var = Q * (1.f / 512.f) - mu * mu;
    float inv = rsqrtf(fmaxf(var, 0.f) + 1e-5f);
    float2 gv = *(const float2*)(g + tid * 2);
    float2 bv = *(const float2*)(b + tid * 2);
    ushort2 o2;
    o2.x = fconv((x0 - mu) * inv * gv.x + bv.x);
    o2.y = fconv((x1 - mu) * inv * gv.y + bv.y);
    *(ushort2*)(h + base) = o2;
}

// ---------------------------------------------------------------------------
// c1sum: out = relu(c0 + c1 + bias) as bf16; row = blockIdx, 2 cols/thread.
// ---------------------------------------------------------------------------
__global__ __launch_bounds__(384) void c1sum_k(
    const float* __restrict__ c0, const float* __restrict__ c1,
    const float* __restrict__ bias, bf16* __restrict__ out)
{
    const long row = blockIdx.x;
    const int col = threadIdx.x * 2;
    const long i = row * 768 + col;
    float2 a = *(const float2*)(c0 + i);
    float2 b2 = *(const float2*)(c1 + i);
    float2 bb = *(const float2*)(bias + col);
    ushort2 o;
    o.x = fconv(fmaxf(a.x + b2.x + bb.x, 0.f));
    o.y = fconv(fmaxf(a.y + b2.y + bb.y, 0.f));
    *(ushort2*)(out + i) = o;
}

__global__ __launch_bounds__(256) void skip_ln_relu_k(
    const float* __restrict__ outp, const bf16* __restrict__ curp, bf16* __restrict__ dst,
    const float* __restrict__ gskip, const float* __restrict__ g, const float* __restrict__ b)
{
    const int row = blockIdx.x;
    const int tid = threadIdx.x;
    const float beta = 1.f / (1.f + __expf(-gskip[0]));
    const long base = (long)row * 512 + tid * 2;
    float2 ov = *(const float2*)(outp + base);
    ushort2 cu = *(const ushort2*)(curp + base);
    float x0 = beta * ov.x + (1.f - beta) * bconv(cu.x);
    float x1 = beta * ov.y + (1.f - beta) * bconv(cu.y);
    float s = x0 + x1;
    float q = x0 * x0 + x1 * x1;
#pragma unroll
    for (int o = 32; o > 0; o >>= 1) { s += __shfl_down(s, o, 64); q += __shfl_down(q, o, 64); }
    __shared__ float ls[4], lq[4];
    if ((tid & 63) == 0) { ls[tid >> 6] = s; lq[tid >> 6] = q; }
    __syncthreads();
    float S = ls[0] + ls[1] + ls[2] + ls[3];
    float Q = lq[0] + lq[1] + lq[2] + lq[3];
    float mu = S * (1.f / 512.f);
    float var = Q * (1.f / 512.f) - mu * mu;
    float inv = rsqrtf(fmaxf(var, 0.f) + 1e-5f);
    float2 gv = *(const float2*)(g + tid * 2);
    float2 bv = *(const float2*)(b + tid * 2);
    ushort2 o2;
    o2.x = fconv(fmaxf((x0 - mu) * inv * gv.x + bv.x, 0.f));
    o2.y = fconv(fmaxf((x1 - mu) * inv * gv.y + bv.y, 0.f));
    *(ushort2*)(dst + base) = o2;
}

// ---------------------------------------------------------------------------
// Edge logits: lg[e][h] = (q[dst[e],h,:] . kj[src[e],h,:]) * prel[h] * scale
// ---------------------------------------------------------------------------
__global__ void edge_logit_k(float* __restrict__ lg, const bf16* __restrict__ qq,
                             const bf16* __restrict__ ktmp, const int* __restrict__ src,
                             const int* __restrict__ dst, const float* __restrict__ prel, int E)
{
    int tid = blockIdx.x * 256 + threadIdx.x;
    int e = tid >> 3;
    int h = tid & 7;
    if (e >= E) return;
    const bf16* qp = qq   + (long)dst[e] * 512 + h * 64;
    const bf16* kp = ktmp + (long)src[e] * 512 + h * 64;
    float acc = 0.f;
#pragma unroll
    for (int i = 0; i < 64; i += 4) {
        float4 a = ld4(qp + i);
        float4 c = ld4(kp + i);
        acc = fmaf(a.x, c.x, acc); acc = fmaf(a.y, c.y, acc);
        acc = fmaf(a.z, c.z, acc); acc = fmaf(a.w, c.w, acc);
    }
    lg[(long)e * 8 + h] = acc * prel[h] * 0.125f;
}

// ---------------------------------------------------------------------------
// CSR build over dst: per dst-type group g (3 groups, 2 edge types each,
// 65536 edges -> 8192 dst nodes). ids pack: (gi<<15) | e.
// ---------------------------------------------------------------------------
__global__ void csr_zero_k(int* __restrict__ off, int* __restrict__ cur)
{
    int i = blockIdx.x * 256 + threadIdx.x;
    if (i < 3 * 8193) off[i] = 0;
    if (i < 3 * 8192) cur[i] = 0;
}

__global__ void csr_count_k(const int* __restrict__ ei, int* __restrict__ off)
{
    int tid = blockIdx.x * 256 + threadIdx.x;       // 3*2*E threads
    int g   = tid >> 16;                             // / 65536
    int rem = tid & 65535;
    int gi  = rem >> 15;
    int e   = rem & (E_EDGES - 1);
    const int GR[6] = {1, 3, 0, 5, 2, 4};
    int r   = GR[g * 2 + gi];
    int dst = ei[((long)r * 2 + 1) * E_EDGES + e];
    atomicAdd(&off[g * 8193 + dst + 1], 1);
}

__global__ __launch_bounds__(256) void csr_scan_k(int* __restrict__ off, int* __restrict__ cur)
{
    const int g = blockIdx.x, t = threadIdx.x;
    int* o = off + g * 8193;
    int v[32];
    int s = 0;
#pragma unroll
    for (int j = 0; j < 32; ++j) { v[j] = o[t * 32 + j + 1]; s += v[j]; }
    __shared__ int ps[256];
    ps[t] = s;
    __syncthreads();
    for (int d = 1; d < 256; d <<= 1) {
        int x = 0;
        if (t >= d) x = ps[t - d];
        __syncthreads();
        if (t >= d) ps[t] += x;
        __syncthreads();
    }
    int run = (t ? ps[t - 1] : 0);
#pragma unroll
    for (int j = 0; j < 32; ++j) {
        cur[g * 8192 + t * 32 + j] = run;   // exclusive prefix = fill cursor
        run += v[j];
        o[t * 32 + j + 1] = run;            // inclusive -> off[d+1]
    }
}

__global__ void csr_fill_k(const int* __restrict__ ei, int* __restrict__ cur,
                           int* __restrict__ ids)
{
    int tid = blockIdx.x * 256 + threadIdx.x;
    int g   = tid >> 16;
    int rem = tid & 65535;
    int gi  = rem >> 15;
    int e   = rem & (E_EDGES - 1);
    const int GR[6] = {1, 3, 0, 5, 2, 4};
    int r   = GR[g * 2 + gi];
    int dst = ei[((long)r * 2 + 1) * E_EDGES + e];
    int p = atomicAdd(&cur[g * 8192 + dst], 1);
    ids[g * 65536 + p] = (gi << 15) | e;
}

// ---------------------------------------------------------------------------
// Fused HGT aggregation: one block per dst node; online segment softmax +
// alpha-weighted gather of mj[src] + GELU. No global atomics.
// ---------------------------------------------------------------------------
__global__ __launch_bounds__(256) void hgt_gather_k(
    const float* __restrict__ lgbuf, const int* __restrict__ ei,
    const int* __restrict__ off, const int* __restrict__ ids,
    const bf16* __restrict__ vt0, const bf16* __restrict__ vt1,
    bf16* __restrict__ aout, int r0, int r1)
{
    const int n = blockIdx.x, tid = threadIdx.x;
    const int beg = off[n], end = off[n + 1];

    __shared__ int   sh_idx[256];
    __shared__ float sh_al[256 * 8];    // logits, then unnormalized alphas
    __shared__ float pm[64];
    __shared__ float mrun[8], srun[8], resc[8];

    if (tid < 8) { mrun[tid] = -1e30f; srun[tid] = 0.f; }
    const int c0 = tid * 2;             // two consecutive channels, same head
    const int h  = tid >> 5;
    float a0 = 0.f, a1 = 0.f;
    __syncthreads();

    for (int t0 = beg; t0 < end; t0 += 256) {
        const int cnt = min(256, end - t0);
        if (tid < cnt) sh_idx[tid] = ids[t0 + tid];
        __syncthreads();
        // stage logits for this tile (coalesced 8-float groups per edge)
        for (int i = tid; i < cnt * 8; i += 256) {
            int idx = sh_idx[i >> 3];
            int gi = idx >> 15, e = idx & 32767;
            int r = gi ? r1 : r0;
            sh_al[i] = lgbuf[((long)r * E_EDGES + e) * 8 + (i & 7)];
        }
        __syncthreads();
        // tile max per head (8 slots x 8 heads)
        if (tid < 64) {
            int hh = tid & 7, sl = tid >> 3;
            float m = -1e30f;
            for (int i = sl; i < cnt; i += 8) m = fmaxf(m, sh_al[i * 8 + hh]);
            pm[tid] = m;
        }
        __syncthreads();
        if (tid < 8) {
            float m = pm[tid];
#pragma unroll
            for (int sl = 1; sl < 8; ++sl) m = fmaxf(m, pm[sl * 8 + tid]);
            float nm = fmaxf(mrun[tid], m);
            resc[tid] = __expf(mrun[tid] - nm);
            mrun[tid] = nm;
        }
        __syncthreads();
        // rescale accumulators; unnormalized alphas in place
        float rs = resc[h];
        a0 *= rs; a1 *= rs;
        for (int i = tid; i < cnt * 8; i += 256)
            sh_al[i] = __expf(sh_al[i] - mrun[i & 7]);
        __syncthreads();
        // tile sum per head
        if (tid < 64) {
            int hh = tid & 7, sl = tid >> 3;
            float s = 0.f;
            for (int i = sl; i < cnt; i += 8) s += sh_al[i * 8 + hh];
            pm[tid] = s;
        }
        __syncthreads();
        if (tid < 8) {
            float s = 0.f;
#pragma unroll
            for (int sl = 0; sl < 8; ++sl) s += pm[sl * 8 + tid];
            srun[tid] = srun[tid] * resc[tid] + s;
        }
        // accumulate alpha * mj[src] (coalesced 4B/lane rows of mj)
        for (int i = 0; i < cnt; ++i) {
            int idx = sh_idx[i];
            int gi = idx >> 15, e = idx & 32767;
            int r = gi ? r1 : r0;
            float al = sh_al[i * 8 + h];
            int src = ei[((long)r * 2) * E_EDGES + e];
            const bf16* v = (gi ? vt1 : vt0) + (long)src * 512 + c0;
            ushort2 u = *(const ushort2*)v;
            a0 = fmaf(al, bconv(u.x), a0);
            a1 = fmaf(al, bconv(u.y), a1);
        }
        __syncthreads();
    }
    float iv = 1.f / (srun[h] + 1e-9f);
    a0 *= iv; a1 *= iv;
    // fused GELU (tanh approx), bf16 store
    float t0v = tanhf(0.79788456080286535588f * (a0 + 0.044715f * a0 * a0 * a0));
    float t1v = tanhf(0.79788456080286535588f * (a1 + 0.044715f * a1 * a1 * a1));
    unsigned short o0 = fconv(0.5f * a0 * (1.f + t0v));
    unsigned short o1 = fconv(0.5f * a1 * (1.f + t1v));
    *(ushort2*)(aout + (long)n * 512 + c0) = make_ushort2(o0, o1);
}

// ---------------------------------------------------------------------------
// concat3: vectorized x8 (512-boundaries are 8-aligned; bit-identical).
// ---------------------------------------------------------------------------
__global__ void concat3_k(const bf16* __restrict__ a, const bf16* __restrict__ b,
                          const bf16* __restrict__ c, bf16* __restrict__ out, int n_oct)
{
    int q = blockIdx.x * 256 + threadIdx.x;
    if (q >= n_oct) return;
    int i = q * 8;
    int n = i / 1536;
    int cc = i - n * 1536;
    const bf16* sp = (cc < 512) ? a : (cc < 1024 ? b : c);
    *(short8*)(out + i) = *(const short8*)(sp + (long)n * 512 + (cc & 511));
}

// ---------------------------------------------------------------------------
static inline void convT(hipStream_t st, const float* in, bf16* out, int K, int N, int z)
{
    dim3 g(N / 32, K / 32, z), b(32, 8);
    transpose_k<<<g, b, 0, st>>>(in, out, K, N);
}
static inline void mgemm(hipStream_t st, const bf16* A, const bf16* Bt, const float* bias,
                         bf16* C, int M, int K, int Ncols, int lda, int ldb, int ldc,
                         long sA, long sB, long sC, long sBias, int z, int act)
{
    dim3 g((Ncols + 63) / 64, M / 64, z);
    mgemm_k<bf16><<<g, 256, 0, st>>>(A, Bt, bias, C, M, K, Ncols, lda, ldb, ldc,
                                     sA, sB, sC, sBias, act);
}
static inline void mgemm_f(hipStream_t st, const bf16* A, const bf16* Bt, const float* bias,
                           float* C, int M, int K, int Ncols, int lda, int ldb, int ldc, int act)
{
    dim3 g((Ncols + 63) / 64, M / 64, 1);
    mgemm_k<float><<<g, 256, 0, st>>>(A, Bt, bias, C, M, K, Ncols, lda, ldb, ldc,
                                      0, 0, 0, 0, act);
}
// split-K (z=2 over K-halves) into two f32 partial buffers C, C + sC
static inline void mgemm_sk2(hipStream_t st, const bf16* A, const bf16* Bt, float* C,
                             int M, int K, int Ncols, int lda, int ldb, int ldc)
{
    dim3 g((Ncols + 63) / 64, M / 64, 2);
    int Kh = K / 2;
    mgemm_k<float><<<g, 256, 0, st>>>(A, Bt, nullptr, C, M, Kh, Ncols, lda, ldb, ldc,
                                      Kh, Kh, (long)M * ldc, 0, 0);
}

extern "C" void kernel_launch(void* const* d_in, const int* in_sizes, int n_in,
                              void* d_out, int out_size, void* d_ws, size_t ws_size,
                              hipStream_t stream)
{
    const float* x_audio = (const float*)d_in[0];
    const float* x_text  = (const float*)d_in[1];
    const float* x_video = (const float*)d_in[2];
    const float* spk_emb = (const float*)d_in[3];
    const float* proj_w  = (const float*)d_in[4];
    const float* proj_b  = (const float*)d_in[5];
    const float* t_qkv_w = (const float*)d_in[6];
    const float* t_qkv_b = (const float*)d_in[7];
    const float* t_out_w = (const float*)d_in[8];
    const float* t_out_b = (const float*)d_in[9];
    const float* t_ff1_w = (const float*)d_in[10];
    const float* t_ff1_b = (const float*)d_in[11];
    const float* t_ff2_w = (const float*)d_in[12];
    const float* t_ff2_b = (const float*)d_in[13];
    const float* t_ln1_g = (const float*)d_in[14];
    const float* t_ln1_b = (const float*)d_in[15];
    const float* t_ln2_g = (const float*)d_in[16];
    const float* t_ln2_b = (const float*)d_in[17];
    const float* g_k_w   = (const float*)d_in[18];
    const float* g_k_b   = (const float*)d_in[19];
    const float* g_q_w   = (const float*)d_in[20];
    const float* g_q_b   = (const float*)d_in[21];
    const float* g_v_w   = (const float*)d_in[22];
    const float* g_v_b   = (const float*)d_in[23];
    const float* g_a_w   = (const float*)d_in[24];
    const float* g_a_b   = (const float*)d_in[25];
    const float* g_skip  = (const float*)d_in[26];
    const float* g_arel  = (const float*)d_in[27];
    const float* g_mrel  = (const float*)d_in[28];
    const float* g_prel  = (const float*)d_in[29];
    const float* g_ln_g  = (const float*)d_in[30];
    const float* g_ln_b  = (const float*)d_in[31];
    const float* c1_w    = (const float*)d_in[32];
    const float* c1_b    = (const float*)d_in[33];
    const float* c2_w    = (const float*)d_in[34];
    const float* c2_b    = (const float*)d_in[35];
    const int* speaker_idx = (const int*)d_in[36];
    const int* edge_index  = (const int*)d_in[38];

    const int N = N_NODES;
    const long NH = (long)N_NODES * H_DIM;

    // ---- bf16-transposed weight region (~56 MB) ----------------------------
    bf16* Wbf = (bf16*)d_ws;
    long off = 0;
    bf16* projT = Wbf + off; off += 3L * 512 * 576;
    bf16* qkvT  = Wbf + off; off += 6L * 1536 * 512;
    bf16* outT  = Wbf + off; off += 6L * 512 * 512;
    bf16* ff1T  = Wbf + off; off += 6L * 2048 * 512;
    bf16* ff2T  = Wbf + off; off += 6L * 512 * 2048;
    bf16* gkT   = Wbf + off; off += 6L * 512 * 512;
    bf16* gqT   = Wbf + off; off += 6L * 512 * 512;
    bf16* gvT   = Wbf + off; off += 6L * 512 * 512;
    bf16* gaT   = Wbf + off; off += 6L * 512 * 512;
    bf16* arelT = Wbf + off; off += 96L * 64 * 64;
    bf16* mrelT = Wbf + off; off += 96L * 64 * 64;
    bf16* c1T   = Wbf + off; off += 768L * 1536;
    off += 4096;  // slack

    // ---- activation workspace (unchanged footprint) ------------------------
    bf16* cur0  = Wbf + off;
    bf16* Kbuf  = cur0 + 3 * NH;
    bf16* QVbuf = Kbuf + 3 * NH;
    bf16* S     = QVbuf + 3 * NH;          // N*2048 scratch
    bf16* aux   = S + (long)N * 2048;      // 2*NH
    bf16* aux2  = aux + NH;

    bf16* xin   = S;
    bf16* qkvb  = S;
    bf16* attno = S + (long)N * 1536;
    bf16* outp  = S;
    bf16* ffb   = S;
    float* agg   = (float*)S;                               // 16.8 MB
    float* lgbuf = agg + NH;                                // 6.3 MB raw logits
    int* csr_off = (int*)(lgbuf + 6L * E_EDGES * 8);        // 3 x 8193
    int* csr_cur = csr_off + 3 * 8193;                      // 3 x 8192
    int* csr_ids = csr_cur + 3 * 8192;                      // 3 x 65536
    bf16* aout   = (bf16*)(csr_ids + 3 * 65536);            // 8.4 MB

    // split-K f32 partials: Kbuf..QVbuf region (50.3 MB, contiguous; free
    // during stage 1+2 and during the classifier)
    float* fsplit = (float*)Kbuf;

    static const int META_S[6] = {0, 1, 0, 2, 1, 2};
    static const int GROUPS[3][2] = {{1, 3}, {0, 5}, {2, 4}};
    const float* xs[3] = {x_audio, x_text, x_video};

    // ---------------- Weight pre-pass ---------------------------------------
    convT(stream, proj_w,  projT, 576, 512, 3);
    convT(stream, t_qkv_w, qkvT,  512, 1536, 6);
    convT(stream, t_out_w, outT,  512, 512, 6);
    convT(stream, t_ff1_w, ff1T,  512, 2048, 6);
    convT(stream, t_ff2_w, ff2T,  2048, 512, 6);
    convT(stream, g_k_w,   gkT,   512, 512, 6);
    convT(stream, g_q_w,   gqT,   512, 512, 6);
    convT(stream, g_v_w,   gvT,   512, 512, 6);
    convT(stream, g_a_w,   gaT,   512, 512, 6);
    convT(stream, g_arel,  arelT, 64, 64, 96);
    convT(stream, g_mrel,  mrelT, 64, 64, 96);
    convT(stream, c1_w,    c1T,   1536, 768, 1);

    // ---------------- Stage 1+2: projection + transformer encoder ----------
    for (int t = 0; t < 3; ++t) {
        bf16* h = cur0 + (long)t * NH;
        xcat_k<<<(N * 576 / 4) / 256, 256, 0, stream>>>(xs[t], spk_emb, speaker_idx,
                                                        xin, N * 576 / 4);
        mgemm(stream, xin, projT + (long)t * 512 * 576, proj_b + (long)t * 512, h,
              N, 576, 512, 576, 576, 512, 0, 0, 0, 0, 1, 0);
        for (int l = 0; l < 2; ++l) {
            long wi = (long)t * 2 + l;
            mgemm(stream, h, qkvT + wi * 1536 * 512, t_qkv_b + wi * 1536, qkvb,
                  N, 512, 1536, 512, 512, 1536, 0, 0, 0, 0, 1, 0);
            attn_mfma_k<<<dim3(D_DLG, N_HEADS), 256, 0, stream>>>(qkvb, attno);
            mgemm(stream, attno, outT + wi * 512 * 512, t_out_b + wi * 512, outp,
                  N, 512, 512, 512, 512, 512, 0, 0, 0, 0, 1, 0);
            add_ln_k<<<N, 256, 0, stream>>>(h, outp, t_ln1_g + wi * 512, t_ln1_b + wi * 512);
            mgemm(stream, h, ff1T + wi * 2048 * 512, t_ff1_b + wi * 2048, ffb,
                  N, 512, 2048, 512, 512, 2048, 0, 0, 0, 0, 1, 1);
            // FF2 split-K (z=2 over K=2048): grid 2048 -> 8 blocks/CU; the
            // two f32 partials + bias fold into add_ln2.
            mgemm_sk2(stream, ffb, ff2T + wi * 512 * 2048, fsplit,
                      N, 2048, 512, 2048, 2048, 512);
            add_ln2_k<<<N, 256, 0, stream>>>(h, fsplit, fsplit + NH,
                                             t_ff2_b + wi * 512,
                                             t_ln2_g + wi * 512, t_ln2_b + wi * 512);
        }
    }

    // ---------------- CSR build (once; edge_index is layer-invariant) -------
    csr_zero_k<<<(3 * 8193 + 255) / 256, 256, 0, stream>>>(csr_off, csr_cur);
    csr_count_k<<<(3 * 2 * E_EDGES) / 256, 256, 0, stream>>>(edge_index, csr_off);
    csr_scan_k<<<3, 256, 0, stream>>>(csr_off, csr_cur);
    csr_fill_k<<<(3 * 2 * E_EDGES) / 256, 256, 0, stream>>>(edge_index, csr_cur, csr_ids);

    // ---------------- Stage 3: HGT layers ----------------------------------
    bf16* cur = cur0;
    for (int l = 0; l < 2; ++l) {
        bf16* Kr  = (l == 0) ? Kbuf : cur0;
        bf16* QVr = QVbuf;
        bf16* nxt = Kr;
        // z-batched K and Q projections over the 3 node types
        mgemm(stream, cur, gkT + (long)l * 3 * 512 * 512, g_k_b + (long)l * 3 * 512, Kr,
              N, 512, 512, 512, 512, 512, NH, 512L * 512, NH, 512, 3, 0);
        mgemm(stream, cur, gqT + (long)l * 3 * 512 * 512, g_q_b + (long)l * 3 * 512, QVr,
              N, 512, 512, 512, 512, 512, NH, 512L * 512, NH, 512, 3, 0);
        for (int r = 0; r < 6; ++r) {
            int st = META_S[r];
            const int META_D[6] = {1, 0, 2, 0, 2, 1};
            int dt = META_D[r];
            const bf16* arel = arelT + ((long)l * 6 + r) * 8 * 64 * 64;
            mgemm(stream, Kr + (long)st * NH, arel, nullptr, aux,
                  N, 64, 64, 512, 64, 512, 64, 64 * 64, 64, 0, 8, 0);
            const int* srcp = edge_index + ((long)r * 2 + 0) * E_EDGES;
            const int* dstp = edge_index + ((long)r * 2 + 1) * E_EDGES;
            edge_logit_k<<<(E_EDGES * 8) / 256, 256, 0, stream>>>(
                lgbuf + (long)r * E_EDGES * 8, QVr + (long)dt * NH, aux,
                srcp, dstp, g_prel + ((long)l * 6 + r) * 8, E_EDGES);
        }
        // z-batched V projection (after edge logits consumed Q from QVr)
        mgemm(stream, cur, gvT + (long)l * 3 * 512 * 512, g_v_b + (long)l * 3 * 512, QVr,
              N, 512, 512, 512, 512, 512, NH, 512L * 512, NH, 512, 3, 0);
        for (int t = 0; t < 3; ++t) {
            int r0 = GROUPS[t][0], r1 = GROUPS[t][1];
            // mj = V @ mrel for the two incoming edge types
            mgemm(stream, QVr + (long)META_S[r0] * NH,
                  mrelT + ((long)l * 6 + r0) * 8 * 64 * 64, nullptr, aux,
                  N, 64, 64, 512, 64, 512, 64, 64 * 64, 64, 0, 8, 0);
            mgemm(stream, QVr + (long)META_S[r1] * NH,
                  mrelT + ((long)l * 6 + r1) * 8 * 64 * 64, nullptr, aux2,
                  N, 64, 64, 512, 64, 512, 64, 64 * 64, 64, 0, 8, 0);
            // fused softmax + gather + GELU (no atomics)
            hgt_gather_k<<<N, 256, 0, stream>>>(lgbuf, edge_index,
                                                csr_off + t * 8193, csr_ids + t * 65536,
                                                aux, aux2, aout, r0, r1);
            long wi = (long)l * 3 + t;
            mgemm_f(stream, aout, gaT + wi * 512 * 512, g_a_b + wi * 512, agg,
                    N, 512, 512, 512, 512, 512, 0);
            skip_ln_relu_k<<<N, 256, 0, stream>>>(agg, cur + (long)t * NH, nxt + (long)t * NH,
                                                  g_skip + (long)l * 3 + t,
                                                  g_ln_g + wi * 512, g_ln_b + wi * 512);
        }
        cur = nxt;
    }

    // ---------------- Classifier (cur == cur0) ------------------------------
    bf16* ci = S;
    bf16* c1out = aux;                      // aux+aux2 free; 12.6 MB needed
    concat3_k<<<(N * 1536 / 8) / 256, 256, 0, stream>>>(cur, cur + NH, cur + 2 * NH,
                                                        ci, N * 1536 / 8);
    // c1 split-K (z=2 over K=1536) into Kbuf/QVbuf f32 partials (50.3 MB fits)
    mgemm_sk2(stream, ci, c1T, fsplit, N, 1536, 768, 1536, 1536, 768);
    c1sum_k<<<N, 384, 0, stream>>>(fsplit, fsplit + (long)N * 768, c1_b, c1out);
    head7_k<<<N / 4, 256, 0, stream>>>(c1out, c2_w, c2_b, (float*)d_out);
}

// Round 10
// 2304.176 us; speedup vs baseline: 1.1085x; 1.1085x over previous
//
#include <hip/hip_runtime.h>
#include <hip/hip_bf16.h>
#include <math.h>

#define N_NODES 8192
#define D_DLG   64
#define L_SEQ   128
#define H_DIM   512
#define N_HEADS 8
#define DHEAD   64
#define FF_DIM  2048
#define E_EDGES 32768

typedef __hip_bfloat16 bf16;
typedef __attribute__((ext_vector_type(8))) short short8;
typedef __attribute__((ext_vector_type(4))) float f32x4;

// ---------------- load/store helpers (bf16 <-> f32) -------------------------
__device__ __forceinline__ float bconv(unsigned short u) {
    return __uint_as_float((unsigned)u << 16);
}
__device__ __forceinline__ unsigned short fconv(float f) {
    bf16 h = __float2bfloat16(f);
    return *(unsigned short*)&h;
}
__device__ __forceinline__ float4 ld4(const float* p) { return *(const float4*)p; }
__device__ __forceinline__ float4 ld4(const bf16* p) {
    ushort4 u = *(const ushort4*)p;
    float4 v;
    v.x = bconv(u.x); v.y = bconv(u.y); v.z = bconv(u.z); v.w = bconv(u.w);
    return v;
}
__device__ __forceinline__ float ld1(const float* p) { return *p; }
__device__ __forceinline__ float ld1(const bf16* p) { return bconv(*(const unsigned short*)p); }
__device__ __forceinline__ void st1(float* p, float v) { *p = v; }
__device__ __forceinline__ void st1(bf16* p, float v) { *p = __float2bfloat16(v); }

__device__ __forceinline__ void gld_lds16(const bf16* g, bf16* l) {
    __builtin_amdgcn_global_load_lds(
        (const __attribute__((address_space(1))) void*)g,
        (__attribute__((address_space(3))) void*)l, 16, 0, 0);
}

// ---------------------------------------------------------------------------
// Weight pre-pass: f32 [z][K][N] -> bf16 [z][N][K] (transpose + convert).
// ---------------------------------------------------------------------------
__global__ __launch_bounds__(256) void transpose_k(const float* __restrict__ in,
                                                   bf16* __restrict__ out, int K, int N)
{
    __shared__ float tile[32][33];
    const long zoff = (long)blockIdx.z * K * N;
    const int n0 = blockIdx.x * 32, k0 = blockIdx.y * 32;
    const int tx = threadIdx.x, ty = threadIdx.y;
#pragma unroll
    for (int i = 0; i < 4; ++i)
        tile[ty + i * 8][tx] = in[zoff + (long)(k0 + ty + i * 8) * N + n0 + tx];
    __syncthreads();
#pragma unroll
    for (int i = 0; i < 4; ++i)
        st1(out + zoff + (long)(n0 + ty + i * 8) * K + k0 + tx, tile[tx][ty + i * 8]);
}

// ---------------------------------------------------------------------------
// MFMA GEMM: C = act(A @ Bt^T + bias). A bf16 [M][K] (lda), Bt bf16 [N][K]
// (ldb), C row-major (ldc). 64x64 tile, BK=64, 4 waves (2x2, 32x32 each).
// R9 post-mortem: occupancy alone (split-K) was neutral -- the BK=32 step's
// ~500cyc barrier drain doesn't overlap across blocks at 8KB/step L2 demand.
// BK=64 doubles per-drain work (8 MFMA + 8 ds_read/wave) and halves drains.
// Bank swizzle: chunk c of row r lives in LDS slot c^(r&7) (inverse XOR on
// the per-lane GLOBAL source; LDS dest linear; read applies the same XOR)
// -> 16-lane b128 column reads are 2-way/bank-group = free. Bijective XCD
// tile swizzle retained. No inline asm; plain __syncthreads pipeline.
// ---------------------------------------------------------------------------
template <typename TC>
__global__ __launch_bounds__(256) void mgemm_k(
    const bf16* __restrict__ A, const bf16* __restrict__ Bt,
    const float* __restrict__ bias, TC* __restrict__ C,
    int M, int K, int Ncols, int lda, int ldb, int ldc,
    long sA, long sB, long sC, long sBias, int act)
{
    A  += (long)blockIdx.z * sA;
    Bt += (long)blockIdx.z * sB;
    C  += (long)blockIdx.z * sC;
    const float* bp = bias ? bias + (long)blockIdx.z * sBias : nullptr;

    __shared__ bf16 As[2][64 * 64];   // 8 KB per buffer
    __shared__ bf16 Bs[2][64 * 64];

    const int tid  = threadIdx.x;
    const int lane = tid & 63;
    const int wave = tid >> 6;
    const int wr   = wave >> 1;
    const int wc   = wave & 1;

    // ---- XCD-aware bijective tile swizzle (all launches have nwg % 8 == 0) -
    const int nwgx = gridDim.x;
    const int nwg  = nwgx * gridDim.y;
    int orig = blockIdx.y * nwgx + blockIdx.x;
    int wgid = ((nwg & 7) == 0) ? ((orig & 7) * (nwg >> 3) + (orig >> 3)) : orig;
    const int rowTile = (wgid / nwgx) * 64;
    const int colTile = (wgid % nwgx) * 64;

    // ---- staging: wave w writes rows w*8..w*8+7 (round 0) / +32 (round 1);
    //      lane l -> row w*8+(l>>3), LDS 16B-slot (l&7); the GLOBAL chunk is
    //      slot ^ (row&7) so that LDS slot s of row r holds chunk s^(r&7) ----
    const int sr0 = wave * 8 + (lane >> 3);
    const int sr1 = sr0 + 32;                       // same (row&7) as sr0
    const int sc  = ((lane & 7) ^ (sr0 & 7)) * 8;   // global k-chunk (elements)

    // ---- fragment read geometry --------------------------------------------
    const int frow = lane & 15;
    const int kgrp = lane >> 4;

    f32x4 acc[2][2];
#pragma unroll
    for (int i = 0; i < 2; ++i)
#pragma unroll
        for (int j = 0; j < 2; ++j) acc[i][j] = (f32x4){0.f, 0.f, 0.f, 0.f};

    const int nk = K >> 6;

#define STAGE(buf, kk)                                                          \
    do {                                                                        \
        gld_lds16(A  + (long)(rowTile + sr0) * lda + (kk) + sc, &As[buf][wave * 512]); \
        gld_lds16(A  + (long)(rowTile + sr1) * lda + (kk) + sc, &As[buf][2048 + wave * 512]); \
        gld_lds16(Bt + (long)(colTile + sr0) * ldb + (kk) + sc, &Bs[buf][wave * 512]); \
        gld_lds16(Bt + (long)(colTile + sr1) * ldb + (kk) + sc, &Bs[buf][2048 + wave * 512]); \
    } while (0)

    auto compute = [&](const bf16* as, const bf16* bs) {
        short8 av[2][2], bv[2][2];
#pragma unroll
        for (int mi = 0; mi < 2; ++mi) {
            int row = wr * 32 + mi * 16 + frow;
#pragma unroll
            for (int ks = 0; ks < 2; ++ks) {
                int slot = ((ks * 4 + kgrp) ^ (frow & 7)) * 8;
                av[mi][ks] = *(const short8*)(as + row * 64 + slot);
            }
        }
#pragma unroll
        for (int ni = 0; ni < 2; ++ni) {
            int row = wc * 32 + ni * 16 + frow;
#pragma unroll
            for (int ks = 0; ks < 2; ++ks) {
                int slot = ((ks * 4 + kgrp) ^ (frow & 7)) * 8;
                bv[ni][ks] = *(const short8*)(bs + row * 64 + slot);
            }
        }
#pragma unroll
        for (int ks = 0; ks < 2; ++ks)
#pragma unroll
            for (int mi = 0; mi < 2; ++mi)
#pragma unroll
                for (int ni = 0; ni < 2; ++ni)
                    acc[mi][ni] = __builtin_amdgcn_mfma_f32_16x16x32_bf16(
                        av[mi][ks], bv[ni][ks], acc[mi][ni], 0, 0, 0);
    };

    STAGE(0, 0);
    __syncthreads();

    for (int t = 0; t < nk; t += 2) {
        if (t + 1 < nk) STAGE(1, (t + 1) * 64);
        compute(As[0], Bs[0]);
        __syncthreads();
        if (t + 1 < nk) {
            if (t + 2 < nk) STAGE(0, (t + 2) * 64);
            compute(As[1], Bs[1]);
            __syncthreads();
        }
    }
#undef STAGE

#pragma unroll
    for (int ni = 0; ni < 2; ++ni) {
        int col = colTile + wc * 32 + ni * 16 + frow;
        if (col < Ncols) {
            float bb = bp ? bp[col] : 0.f;
#pragma unroll
            for (int mi = 0; mi < 2; ++mi) {
                long rbase = rowTile + wr * 32 + mi * 16 + kgrp * 4;
#pragma unroll
                for (int r = 0; r < 4; ++r) {
                    float v = acc[mi][ni][r] + bb;
                    if (act == 1) v = fmaxf(v, 0.f);
                    st1(C + (rbase + r) * (long)ldc + col, v);
                }
            }
        }
    }
}

// ---------------------------------------------------------------------------
// MFMA flash attention per (dialogue, head). 256 thr = 4 waves.
// ---------------------------------------------------------------------------
__global__ __launch_bounds__(256) void attn_mfma_k(const bf16* __restrict__ qkv,
                                                   bf16* __restrict__ o)
{
    __shared__ bf16 Pb[128 * 136];   // 34.8 KB, A-layout P
    __shared__ bf16 Vt[64 * 136];    // 17.4 KB, V^T [dh][l]
    __shared__ float pm[128][2];     // per-row partial max (per wave-col)
    __shared__ float ps[128][2];     // per-row partial sum

    const int d = blockIdx.x, h = blockIdx.y;
    const long base = (long)d * L_SEQ;
    const int tid  = threadIdx.x;
    const int lane = tid & 63;
    const int wave = tid >> 6;
    const int frow = lane & 15;
    const int kgrp = lane >> 4;
    const int wr = wave >> 1;        // S row-half
    const int wc = wave & 1;         // S col-half
    const float SC = 0.125f;

    // ---- V[l][dh] -> Vt[dh][l] (one-time scalar transpose) -----------------
    {
        int l = tid >> 1, dh0 = (tid & 1) * 32;
        const bf16* vp = qkv + (base + l) * 1536 + 1024 + h * 64 + dh0;
        unsigned short* vt = (unsigned short*)Vt;
#pragma unroll
        for (int j = 0; j < 4; ++j) {
            short8 v = *(const short8*)(vp + j * 8);
#pragma unroll
            for (int jj = 0; jj < 8; ++jj)
                vt[(dh0 + j * 8 + jj) * 136 + l] = (unsigned short)v[jj];
        }
    }

    // ---- Q,K fragments direct from global (no reuse -> no LDS) -------------
    short8 aq[4][2], bk[4][2];
#pragma unroll
    for (int mi = 0; mi < 4; ++mi) {
        long row = base + wr * 64 + mi * 16 + frow;
#pragma unroll
        for (int ks = 0; ks < 2; ++ks)
            aq[mi][ks] = *(const short8*)(qkv + row * 1536 + h * 64 + ks * 32 + kgrp * 8);
    }
#pragma unroll
    for (int ni = 0; ni < 4; ++ni) {
        long row = base + wc * 64 + ni * 16 + frow;
#pragma unroll
        for (int ks = 0; ks < 2; ++ks)
            bk[ni][ks] = *(const short8*)(qkv + row * 1536 + 512 + h * 64 + ks * 32 + kgrp * 8);
    }

    // ---- S = Q @ K^T (64x64 per wave) --------------------------------------
    f32x4 acc[4][4];
#pragma unroll
    for (int i = 0; i < 4; ++i)
#pragma unroll
        for (int j = 0; j < 4; ++j) acc[i][j] = (f32x4){0.f, 0.f, 0.f, 0.f};
#pragma unroll
    for (int ks = 0; ks < 2; ++ks)
#pragma unroll
        for (int mi = 0; mi < 4; ++mi)
#pragma unroll
            for (int ni = 0; ni < 4; ++ni)
                acc[mi][ni] = __builtin_amdgcn_mfma_f32_16x16x32_bf16(
                    aq[mi][ks], bk[ni][ks], acc[mi][ni], 0, 0, 0);

    // ---- per-wave row partials ---------------------------------------------
#pragma unroll
    for (int mi = 0; mi < 4; ++mi) {
#pragma unroll
        for (int r = 0; r < 4; ++r) {
            float mv = -1e30f;
#pragma unroll
            for (int ni = 0; ni < 4; ++ni) mv = fmaxf(mv, acc[mi][ni][r] * SC);
#pragma unroll
            for (int off = 1; off < 16; off <<= 1)
                mv = fmaxf(mv, __shfl_xor(mv, off, 64));
            float sv = 0.f;
#pragma unroll
            for (int ni = 0; ni < 4; ++ni) sv += __expf(acc[mi][ni][r] * SC - mv);
#pragma unroll
            for (int off = 1; off < 16; off <<= 1)
                sv += __shfl_xor(sv, off, 64);
            if (frow == 0) {
                int row = wr * 64 + mi * 16 + kgrp * 4 + r;
                pm[row][wc] = mv;
                ps[row][wc] = sv;
            }
        }
    }
    __syncthreads();

    // ---- merge halves, write P (bf16, A-layout) ----------------------------
    unsigned short* pb = (unsigned short*)Pb;
#pragma unroll
    for (int mi = 0; mi < 4; ++mi) {
#pragma unroll
        for (int r = 0; r < 4; ++r) {
            int row = wr * 64 + mi * 16 + kgrp * 4 + r;
            float m0 = pm[row][0], m1 = pm[row][1];
            float M = fmaxf(m0, m1);
            float Ssum = ps[row][0] * __expf(m0 - M) + ps[row][1] * __expf(m1 - M);
            float inv = 1.f / Ssum;
#pragma unroll
            for (int ni = 0; ni < 4; ++ni) {
                int col = wc * 64 + ni * 16 + frow;
                float p = __expf(acc[mi][ni][r] * SC - M) * inv;
                pb[row * 136 + col] = fconv(p);
            }
        }
    }
    __syncthreads();

    // ---- O = P @ V ----------------------------------------------------------
    f32x4 acc2[2][4];
#pragma unroll
    for (int i = 0; i < 2; ++i)
#pragma unroll
        for (int j = 0; j < 4; ++j) acc2[i][j] = (f32x4){0.f, 0.f, 0.f, 0.f};
#pragma unroll
    for (int ks = 0; ks < 4; ++ks) {
        short8 ap[2], bv[4];
#pragma unroll
        for (int mi = 0; mi < 2; ++mi)
            ap[mi] = *(const short8*)(Pb + (wave * 32 + mi * 16 + frow) * 136 + ks * 32 + kgrp * 8);
#pragma unroll
        for (int ni = 0; ni < 4; ++ni)
            bv[ni] = *(const short8*)(Vt + (ni * 16 + frow) * 136 + ks * 32 + kgrp * 8);
#pragma unroll
        for (int mi = 0; mi < 2; ++mi)
#pragma unroll
            for (int ni = 0; ni < 4; ++ni)
                acc2[mi][ni] = __builtin_amdgcn_mfma_f32_16x16x32_bf16(
                    ap[mi], bv[ni], acc2[mi][ni], 0, 0, 0);
    }
#pragma unroll
    for (int mi = 0; mi < 2; ++mi) {
#pragma unroll
        for (int ni = 0; ni < 4; ++ni) {
            int col = ni * 16 + frow;
            long rowb = wave * 32 + mi * 16 + kgrp * 4;
#pragma unroll
            for (int r = 0; r < 4; ++r)
                st1(o + (base + rowb + r) * 512 + h * 64 + col, acc2[mi][ni][r]);
        }
    }
}

// ---------------------------------------------------------------------------
// Classifier head: out[N,7] = A[N,768] @ W[768,7] + bias. Wave per row.
// ---------------------------------------------------------------------------
__global__ __launch_bounds__(256) void head7_k(
    const bf16* __restrict__ A, const float* __restrict__ W,
    const float* __restrict__ bias, float* __restrict__ out)
{
    const int wave = threadIdx.x >> 6, lane = threadIdx.x & 63;
    const long row = blockIdx.x * 4 + wave;
    const bf16* a = A + row * 768;
    float acc[7];
#pragma unroll
    for (int j = 0; j < 7; ++j) acc[j] = 0.f;
#pragma unroll
    for (int i = 0; i < 12; ++i) {
        int k = lane + i * 64;
        float av = ld1(a + k);
        const float* w = W + k * 7;
#pragma unroll
        for (int j = 0; j < 7; ++j) acc[j] = fmaf(av, w[j], acc[j]);
    }
#pragma unroll
    for (int j = 0; j < 7; ++j)
#pragma unroll
        for (int o = 32; o > 0; o >>= 1) acc[j] += __shfl_down(acc[j], o, 64);
    if (lane == 0) {
#pragma unroll
        for (int j = 0; j < 7; ++j) out[row * 7 + j] = acc[j] + bias[j];
    }
}

// ---------------------------------------------------------------------------
// xcat: vectorized x4 (4-aligned quads never straddle source regions).
// ---------------------------------------------------------------------------
__global__ void xcat_k(const float* __restrict__ x, const float* __restrict__ spk_emb,
                       const int* __restrict__ sidx, bf16* __restrict__ out, int n_quads)
{
    int q = blockIdx.x * 256 + threadIdx.x;
    if (q >= n_quads) return;
    int i = q * 4;
    int n = i / 576;
    int c = i - n * 576;
    const float* sp = (c < 512) ? (x + (long)n * 512 + c)
                                : (spk_emb + (long)sidx[n] * 64 + (c - 512));
    float4 v = *(const float4*)sp;
    ushort4 u;
    u.x = fconv(v.x); u.y = fconv(v.y); u.z = fconv(v.z); u.w = fconv(v.w);
    *(ushort4*)(out + i) = u;
}

// ---------------------------------------------------------------------------
// add_ln: pair-loads; residual r is bf16.
// ---------------------------------------------------------------------------
__global__ __launch_bounds__(256) void add_ln_k(bf16* __restrict__ h, const bf16* __restrict__ r,
                                                const float* __restrict__ g, const float* __restrict__ b)
{
    const int row = blockIdx.x;
    const int tid = threadIdx.x;
    const long base = (long)row * 512 + tid * 2;
    ushort2 hu = *(const ushort2*)(h + base);
    ushort2 ru = *(const ushort2*)(r + base);
    float x0 = bconv(hu.x) + bconv(ru.x);
    float x1 = bconv(hu.y) + bconv(ru.y);
    float s = x0 + x1;
    float q = x0 * x0 + x1 * x1;
#pragma unroll
    for (int o = 32; o > 0; o >>= 1) { s += __shfl_down(s, o, 64); q += __shfl_down(q, o, 64); }
    __shared__ float ls[4], lq[4];
    if ((tid & 63) == 0) { ls[tid >> 6] = s; lq[tid >> 6] = q; }
    __syncthreads();
    float S = ls[0] + ls[1] + ls[2] + ls[3];
    float Q = lq[0] + lq[1] + lq[2] + lq[3];
    float mu = S * (1.f / 512.f);
    float var = Q * (1.f / 512.f) - mu * mu;
    float inv = rsqrtf(fmaxf(var, 0.f) + 1e-5f);
    float2 gv = *(const float2*)(g + tid * 2);
    float2 bv = *(const float2*)(b + tid * 2);
    ushort2 o2;
    o2.x = fconv((x0 - mu) * inv * gv.x + bv.x);
    o2.y = fconv((x1 - mu) * inv * gv.y + bv.y);
    *(ushort2*)(h + base) = o2;
}

__global__ __launch_bounds__(256) void skip_ln_relu_k(
    const float* __restrict__ outp, const bf16* __restrict__ curp, bf16* __restrict__ dst,
    const float* __restrict__ gskip, const float* __restrict__ g, const float* __restrict__ b)
{
    const int row = blockIdx.x;
    const int tid = threadIdx.x;
    const float beta = 1.f / (1.f + __expf(-gskip[0]));
    const long base = (long)row * 512 + tid * 2;
    float2 ov = *(const float2*)(outp + base);
    ushort2 cu = *(const ushort2*)(curp + base);
    float x0 = beta * ov.x + (1.f - beta) * bconv(cu.x);
    float x1 = beta * ov.y + (1.f - beta) * bconv(cu.y);
    float s = x0 + x1;
    float q = x0 * x0 + x1 * x1;
#pragma unroll
    for (int o = 32; o > 0; o >>= 1) { s += __shfl_down(s, o, 64); q += __shfl_down(q, o, 64); }
    __shared__ float ls[4], lq[4];
    if ((tid & 63) == 0) { ls[tid >> 6] = s; lq[tid >> 6] = q; }
    __syncthreads();
    float S = ls[0] + ls[1] + ls[2] + ls[3];
    float Q = lq[0] + lq[1] + lq[2] + lq[3];
    float mu = S * (1.f / 512.f);
    float var = Q * (1.f / 512.f) - mu * mu;
    float inv = rsqrtf(fmaxf(var, 0.f) + 1e-5f);
    float2 gv = *(const float2*)(g + tid * 2);
    float2 bv = *(const float2*)(b + tid * 2);
    ushort2 o2;
    o2.x = fconv(fmaxf((x0 - mu) * inv * gv.x + bv.x, 0.f));
    o2.y = fconv(fmaxf((x1 - mu) * inv * gv.y + bv.y, 0.f));
    *(ushort2*)(dst + base) = o2;
}

// ---------------------------------------------------------------------------
// Edge logits: lg[e][h] = (q[dst[e],h,:] . kj[src[e],h,:]) * prel[h] * scale
// ---------------------------------------------------------------------------
__global__ void edge_logit_k(float* __restrict__ lg, const bf16* __restrict__ qq,
                             const bf16* __restrict__ ktmp, const int* __restrict__ src,
                             const int* __restrict__ dst, const float* __restrict__ prel, int E)
{
    int tid = blockIdx.x * 256 + threadIdx.x;
    int e = tid >> 3;
    int h = tid & 7;
    if (e >= E) return;
    const bf16* qp = qq   + (long)dst[e] * 512 + h * 64;
    const bf16* kp = ktmp + (long)src[e] * 512 + h * 64;
    float acc = 0.f;
#pragma unroll
    for (int i = 0; i < 64; i += 4) {
        float4 a = ld4(qp + i);
        float4 c = ld4(kp + i);
        acc = fmaf(a.x, c.x, acc); acc = fmaf(a.y, c.y, acc);
        acc = fmaf(a.z, c.z, acc); acc = fmaf(a.w, c.w, acc);
    }
    lg[(long)e * 8 + h] = acc * prel[h] * 0.125f;
}

// ---------------------------------------------------------------------------
// CSR build over dst: per dst-type group g (3 groups, 2 edge types each,
// 65536 edges -> 8192 dst nodes). ids pack: (gi<<15) | e.
// ---------------------------------------------------------------------------
__global__ void csr_zero_k(int* __restrict__ off, int* __restrict__ cur)
{
    int i = blockIdx.x * 256 + threadIdx.x;
    if (i < 3 * 8193) off[i] = 0;
    if (i < 3 * 8192) cur[i] = 0;
}

__global__ void csr_count_k(const int* __restrict__ ei, int* __restrict__ off)
{
    int tid = blockIdx.x * 256 + threadIdx.x;       // 3*2*E threads
    int g   = tid >> 16;                             // / 65536
    int rem = tid & 65535;
    int gi  = rem >> 15;
    int e   = rem & (E_EDGES - 1);
    const int GR[6] = {1, 3, 0, 5, 2, 4};
    int r   = GR[g * 2 + gi];
    int dst = ei[((long)r * 2 + 1) * E_EDGES + e];
    atomicAdd(&off[g * 8193 + dst + 1], 1);
}

__global__ __launch_bounds__(256) void csr_scan_k(int* __restrict__ off, int* __restrict__ cur)
{
    const int g = blockIdx.x, t = threadIdx.x;
    int* o = off + g * 8193;
    int v[32];
    int s = 0;
#pragma unroll
    for (int j = 0; j < 32; ++j) { v[j] = o[t * 32 + j + 1]; s += v[j]; }
    __shared__ int ps[256];
    ps[t] = s;
    __syncthreads();
    for (int d = 1; d < 256; d <<= 1) {
        int x = 0;
        if (t >= d) x = ps[t - d];
        __syncthreads();
        if (t >= d) ps[t] += x;
        __syncthreads();
    }
    int run = (t ? ps[t - 1] : 0);
#pragma unroll
    for (int j = 0; j < 32; ++j) {
        cur[g * 8192 + t * 32 + j] = run;   // exclusive prefix = fill cursor
        run += v[j];
        o[t * 32 + j + 1] = run;            // inclusive -> off[d+1]
    }
}

__global__ void csr_fill_k(const int* __restrict__ ei, int* __restrict__ cur,
                           int* __restrict__ ids)
{
    int tid = blockIdx.x * 256 + threadIdx.x;
    int g   = tid >> 16;
    int rem = tid & 65535;
    int gi  = rem >> 15;
    int e   = rem & (E_EDGES - 1);
    const int GR[6] = {1, 3, 0, 5, 2, 4};
    int r   = GR[g * 2 + gi];
    int dst = ei[((long)r * 2 + 1) * E_EDGES + e];
    int p = atomicAdd(&cur[g * 8192 + dst], 1);
    ids[g * 65536 + p] = (gi << 15) | e;
}

// ---------------------------------------------------------------------------
// Fused HGT aggregation: one block per dst node; online segment softmax +
// alpha-weighted gather of mj[src] + GELU. No global atomics.
// ---------------------------------------------------------------------------
__global__ __launch_bounds__(256) void hgt_gather_k(
    const float* __restrict__ lgbuf, const int* __restrict__ ei,
    const int* __restrict__ off, const int* __restrict__ ids,
    const bf16* __restrict__ vt0, const bf16* __restrict__ vt1,
    bf16* __restrict__ aout, int r0, int r1)
{
    const int n = blockIdx.x, tid = threadIdx.x;
    const int beg = off[n], end = off[n + 1];

    __shared__ int   sh_idx[256];
    __shared__ float sh_al[256 * 8];    // logits, then unnormalized alphas
    __shared__ float pm[64];
    __shared__ float mrun[8], srun[8], resc[8];

    if (tid < 8) { mrun[tid] = -1e30f; srun[tid] = 0.f; }
    const int c0 = tid * 2;             // two consecutive channels, same head
    const int h  = tid >> 5;
    float a0 = 0.f, a1 = 0.f;
    __syncthreads();

    for (int t0 = beg; t0 < end; t0 += 256) {
        const int cnt = min(256, end - t0);
        if (tid < cnt) sh_idx[tid] = ids[t0 + tid];
        __syncthreads();
        // stage logits for this tile (coalesced 8-float groups per edge)
        for (int i = tid; i < cnt * 8; i += 256) {
            int idx = sh_idx[i >> 3];
            int gi = idx >> 15, e = idx & 32767;
            int r = gi ? r1 : r0;
            sh_al[i] = lgbuf[((long)r * E_EDGES + e) * 8 + (i & 7)];
        }
        __syncthreads();
        // tile max per head (8 slots x 8 heads)
        if (tid < 64) {
            int hh = tid & 7, sl = tid >> 3;
            float m = -1e30f;
            for (int i = sl; i < cnt; i += 8) m = fmaxf(m, sh_al[i * 8 + hh]);
            pm[tid] = m;
        }
        __syncthreads();
        if (tid < 8) {
            float m = pm[tid];
#pragma unroll
            for (int sl = 1; sl < 8; ++sl) m = fmaxf(m, pm[sl * 8 + tid]);
            float nm = fmaxf(mrun[tid], m);
            resc[tid] = __expf(mrun[tid] - nm);
            mrun[tid] = nm;
        }
        __syncthreads();
        // rescale accumulators; unnormalized alphas in place
        float rs = resc[h];
        a0 *= rs; a1 *= rs;
        for (int i = tid; i < cnt * 8; i += 256)
            sh_al[i] = __expf(sh_al[i] - mrun[i & 7]);
        __syncthreads();
        // tile sum per head
        if (tid < 64) {
            int hh = tid & 7, sl = tid >> 3;
            float s = 0.f;
            for (int i = sl; i < cnt; i += 8) s += sh_al[i * 8 + hh];
            pm[tid] = s;
        }
        __syncthreads();
        if (tid < 8) {
            float s = 0.f;
#pragma unroll
            for (int sl = 0; sl < 8; ++sl) s += pm[sl * 8 + tid];
            srun[tid] = srun[tid] * resc[tid] + s;
        }
        // accumulate alpha * mj[src] (coalesced 4B/lane rows of mj)
        for (int i = 0; i < cnt; ++i) {
            int idx = sh_idx[i];
            int gi = idx >> 15, e = idx & 32767;
            int r = gi ? r1 : r0;
            float al = sh_al[i * 8 + h];
            int src = ei[((long)r * 2) * E_EDGES + e];
            const bf16* v = (gi ? vt1 : vt0) + (long)src * 512 + c0;
            ushort2 u = *(const ushort2*)v;
            a0 = fmaf(al, bconv(u.x), a0);
            a1 = fmaf(al, bconv(u.y), a1);
        }
        __syncthreads();
    }
    float iv = 1.f / (srun[h] + 1e-9f);
    a0 *= iv; a1 *= iv;
    // fused GELU (tanh approx), bf16 store
    float t0v = tanhf(0.79788456080286535588f * (a0 + 0.044715f * a0 * a0 * a0));
    float t1v = tanhf(0.79788456080286535588f * (a1 + 0.044715f * a1 * a1 * a1));
    unsigned short o0 = fconv(0.5f * a0 * (1.f + t0v));
    unsigned short o1 = fconv(0.5f * a1 * (1.f + t1v));
    *(ushort2*)(aout + (long)n * 512 + c0) = make_ushort2(o0, o1);
}

// ---------------------------------------------------------------------------
// concat3: vectorized x8 (512-boundaries are 8-aligned; bit-identical).
// ---------------------------------------------------------------------------
__global__ void concat3_k(const bf16* __restrict__ a, const bf16* __restrict__ b,
                          const bf16* __restrict__ c, bf16* __restrict__ out, int n_oct)
{
    int q = blockIdx.x * 256 + threadIdx.x;
    if (q >= n_oct) return;
    int i = q * 8;
    int n = i / 1536;
    int cc = i - n * 1536;
    const bf16* sp = (cc < 512) ? a : (cc < 1024 ? b : c);
    *(short8*)(out + i) = *(const short8*)(sp + (long)n * 512 + (cc & 511));
}

// ---------------------------------------------------------------------------
static inline void convT(hipStream_t st, const float* in, bf16* out, int K, int N, int z)
{
    dim3 g(N / 32, K / 32, z), b(32, 8);
    transpose_k<<<g, b, 0, st>>>(in, out, K, N);
}
static inline void mgemm(hipStream_t st, const bf16* A, const bf16* Bt, const float* bias,
                         bf16* C, int M, int K, int Ncols, int lda, int ldb, int ldc,
                         long sA, long sB, long sC, long sBias, int z, int act)
{
    dim3 g((Ncols + 63) / 64, M / 64, z);
    mgemm_k<bf16><<<g, 256, 0, st>>>(A, Bt, bias, C, M, K, Ncols, lda, ldb, ldc,
                                     sA, sB, sC, sBias, act);
}
static inline void mgemm_f(hipStream_t st, const bf16* A, const bf16* Bt, const float* bias,
                           float* C, int M, int K, int Ncols, int lda, int ldb, int ldc, int act)
{
    dim3 g((Ncols + 63) / 64, M / 64, 1);
    mgemm_k<float><<<g, 256, 0, st>>>(A, Bt, bias, C, M, K, Ncols, lda, ldb, ldc,
                                      0, 0, 0, 0, act);
}

extern "C" void kernel_launch(void* const* d_in, const int* in_sizes, int n_in,
                              void* d_out, int out_size, void* d_ws, size_t ws_size,
                              hipStream_t stream)
{
    const float* x_audio = (const float*)d_in[0];
    const float* x_text  = (const float*)d_in[1];
    const float* x_video = (const float*)d_in[2];
    const float* spk_emb = (const float*)d_in[3];
    const float* proj_w  = (const float*)d_in[4];
    const float* proj_b  = (const float*)d_in[5];
    const float* t_qkv_w = (const float*)d_in[6];
    const float* t_qkv_b = (const float*)d_in[7];
    const float* t_out_w = (const float*)d_in[8];
    const float* t_out_b = (const float*)d_in[9];
    const float* t_ff1_w = (const float*)d_in[10];
    const float* t_ff1_b = (const float*)d_in[11];
    const float* t_ff2_w = (const float*)d_in[12];
    const float* t_ff2_b = (const float*)d_in[13];
    const float* t_ln1_g = (const float*)d_in[14];
    const float* t_ln1_b = (const float*)d_in[15];
    const float* t_ln2_g = (const float*)d_in[16];
    const float* t_ln2_b = (const float*)d_in[17];
    const float* g_k_w   = (const float*)d_in[18];
    const float* g_k_b   = (const float*)d_in[19];
    const float* g_q_w   = (const float*)d_in[20];
    const float* g_q_b   = (const float*)d_in[21];
    const float* g_v_w   = (const float*)d_in[22];
    const float* g_v_b   = (const float*)d_in[23];
    const float* g_a_w   = (const float*)d_in[24];
    const float* g_a_b   = (const float*)d_in[25];
    const float* g_skip  = (const float*)d_in[26];
    const float* g_arel  = (const float*)d_in[27];
    const float* g_mrel  = (const float*)d_in[28];
    const float* g_prel  = (const float*)d_in[29];
    const float* g_ln_g  = (const float*)d_in[30];
    const float* g_ln_b  = (const float*)d_in[31];
    const float* c1_w    = (const float*)d_in[32];
    const float* c1_b    = (const float*)d_in[33];
    const float* c2_w    = (const float*)d_in[34];
    const float* c2_b    = (const float*)d_in[35];
    const int* speaker_idx = (const int*)d_in[36];
    const int* edge_index  = (const int*)d_in[38];

    const int N = N_NODES;
    const long NH = (long)N_NODES * H_DIM;

    // ---- bf16-transposed weight region (~56 MB) ----------------------------
    bf16* Wbf = (bf16*)d_ws;
    long off = 0;
    bf16* projT = Wbf + off; off += 3L * 512 * 576;
    bf16* qkvT  = Wbf + off; off += 6L * 1536 * 512;
    bf16* outT  = Wbf + off; off += 6L * 512 * 512;
    bf16* ff1T  = Wbf + off; off += 6L * 2048 * 512;
    bf16* ff2T  = Wbf + off; off += 6L * 512 * 2048;
    bf16* gkT   = Wbf + off; off += 6L * 512 * 512;
    bf16* gqT   = Wbf + off; off += 6L * 512 * 512;
    bf16* gvT   = Wbf + off; off += 6L * 512 * 512;
    bf16* gaT   = Wbf + off; off += 6L * 512 * 512;
    bf16* arelT = Wbf + off; off += 96L * 64 * 64;
    bf16* mrelT = Wbf + off; off += 96L * 64 * 64;
    bf16* c1T   = Wbf + off; off += 768L * 1536;
    off += 4096;  // slack

    // ---- activation workspace (unchanged footprint) ------------------------
    bf16* cur0  = Wbf + off;
    bf16* Kbuf  = cur0 + 3 * NH;
    bf16* QVbuf = Kbuf + 3 * NH;
    bf16* S     = QVbuf + 3 * NH;          // N*2048 scratch
    bf16* aux   = S + (long)N * 2048;      // 2*NH
    bf16* aux2  = aux + NH;

    bf16* xin   = S;
    bf16* qkvb  = S;
    bf16* attno = S + (long)N * 1536;
    bf16* outp  = S;
    bf16* ffb   = S;
    float* agg   = (float*)S;                               // 16.8 MB
    float* lgbuf = agg + NH;                                // 6.3 MB raw logits
    int* csr_off = (int*)(lgbuf + 6L * E_EDGES * 8);        // 3 x 8193
    int* csr_cur = csr_off + 3 * 8193;                      // 3 x 8192
    int* csr_ids = csr_cur + 3 * 8192;                      // 3 x 65536
    bf16* aout   = (bf16*)(csr_ids + 3 * 65536);            // 8.4 MB

    static const int META_S[6] = {0, 1, 0, 2, 1, 2};
    static const int GROUPS[3][2] = {{1, 3}, {0, 5}, {2, 4}};
    const float* xs[3] = {x_audio, x_text, x_video};

    // ---------------- Weight pre-pass ---------------------------------------
    convT(stream, proj_w,  projT, 576, 512, 3);
    convT(stream, t_qkv_w, qkvT,  512, 1536, 6);
    convT(stream, t_out_w, outT,  512, 512, 6);
    convT(stream, t_ff1_w, ff1T,  512, 2048, 6);
    convT(stream, t_ff2_w, ff2T,  2048, 512, 6);
    convT(stream, g_k_w,   gkT,   512, 512, 6);
    convT(stream, g_q_w,   gqT,   512, 512, 6);
    convT(stream, g_v_w,   gvT,   512, 512, 6);
    convT(stream, g_a_w,   gaT,   512, 512, 6);
    convT(stream, g_arel,  arelT, 64, 64, 96);
    convT(stream, g_mrel,  mrelT, 64, 64, 96);
    convT(stream, c1_w,    c1T,   1536, 768, 1);

    // ---------------- Stage 1+2: projection + transformer encoder ----------
    for (int t = 0; t < 3; ++t) {
        bf16* h = cur0 + (long)t * NH;
        xcat_k<<<(N * 576 / 4) / 256, 256, 0, stream>>>(xs[t], spk_emb, speaker_idx,
                                                        xin, N * 576 / 4);
        mgemm(stream, xin, projT + (long)t * 512 * 576, proj_b + (long)t * 512, h,
              N, 576, 512, 576, 576, 512, 0, 0, 0, 0, 1, 0);
        for (int l = 0; l < 2; ++l) {
            long wi = (long)t * 2 + l;
            mgemm(stream, h, qkvT + wi * 1536 * 512, t_qkv_b + wi * 1536, qkvb,
                  N, 512, 1536, 512, 512, 1536, 0, 0, 0, 0, 1, 0);
            attn_mfma_k<<<dim3(D_DLG, N_HEADS), 256, 0, stream>>>(qkvb, attno);
            mgemm(stream, attno, outT + wi * 512 * 512, t_out_b + wi * 512, outp,
                  N, 512, 512, 512, 512, 512, 0, 0, 0, 0, 1, 0);
            add_ln_k<<<N, 256, 0, stream>>>(h, outp, t_ln1_g + wi * 512, t_ln1_b + wi * 512);
            mgemm(stream, h, ff1T + wi * 2048 * 512, t_ff1_b + wi * 2048, ffb,
                  N, 512, 2048, 512, 512, 2048, 0, 0, 0, 0, 1, 1);
            mgemm(stream, ffb, ff2T + wi * 512 * 2048, t_ff2_b + wi * 512, aux,
                  N, 2048, 512, 2048, 2048, 512, 0, 0, 0, 0, 1, 0);
            add_ln_k<<<N, 256, 0, stream>>>(h, aux, t_ln2_g + wi * 512, t_ln2_b + wi * 512);
        }
    }

    // ---------------- CSR build (once; edge_index is layer-invariant) -------
    csr_zero_k<<<(3 * 8193 + 255) / 256, 256, 0, stream>>>(csr_off, csr_cur);
    csr_count_k<<<(3 * 2 * E_EDGES) / 256, 256, 0, stream>>>(edge_index, csr_off);
    csr_scan_k<<<3, 256, 0, stream>>>(csr_off, csr_cur);
    csr_fill_k<<<(3 * 2 * E_EDGES) / 256, 256, 0, stream>>>(edge_index, csr_cur, csr_ids);

    // ---------------- Stage 3: HGT layers ----------------------------------
    bf16* cur = cur0;
    for (int l = 0; l < 2; ++l) {
        bf16* Kr  = (l == 0) ? Kbuf : cur0;
        bf16* QVr = QVbuf;
        bf16* nxt = Kr;
        // z-batched K and Q projections over the 3 node types
        mgemm(stream, cur, gkT + (long)l * 3 * 512 * 512, g_k_b + (long)l * 3 * 512, Kr,
              N, 512, 512, 512, 512, 512, NH, 512L * 512, NH, 512, 3, 0);
        mgemm(stream, cur, gqT + (long)l * 3 * 512 * 512, g_q_b + (long)l * 3 * 512, QVr,
              N, 512, 512, 512, 512, 512, NH, 512L * 512, NH, 512, 3, 0);
        for (int r = 0; r < 6; ++r) {
            int st = META_S[r];
            const int META_D[6] = {1, 0, 2, 0, 2, 1};
            int dt = META_D[r];
            const bf16* arel = arelT + ((long)l * 6 + r) * 8 * 64 * 64;
            mgemm(stream, Kr + (long)st * NH, arel, nullptr, aux,
                  N, 64, 64, 512, 64, 512, 64, 64 * 64, 64, 0, 8, 0);
            const int* srcp = edge_index + ((long)r * 2 + 0) * E_EDGES;
            const int* dstp = edge_index + ((long)r * 2 + 1) * E_EDGES;
            edge_logit_k<<<(E_EDGES * 8) / 256, 256, 0, stream>>>(
                lgbuf + (long)r * E_EDGES * 8, QVr + (long)dt * NH, aux,
                srcp, dstp, g_prel + ((long)l * 6 + r) * 8, E_EDGES);
        }
        // z-batched V projection (after edge logits consumed Q from QVr)
        mgemm(stream, cur, gvT + (long)l * 3 * 512 * 512, g_v_b + (long)l * 3 * 512, QVr,
              N, 512, 512, 512, 512, 512, NH, 512L * 512, NH, 512, 3, 0);
        for (int t = 0; t < 3; ++t) {
            int r0 = GROUPS[t][0], r1 = GROUPS[t][1];
            // mj = V @ mrel for the two incoming edge types
            mgemm(stream, QVr + (long)META_S[r0] * NH,
                  mrelT + ((long)l * 6 + r0) * 8 * 64 * 64, nullptr, aux,
                  N, 64, 64, 512, 64, 512, 64, 64 * 64, 64, 0, 8, 0);
            mgemm(stream, QVr + (long)META_S[r1] * NH,
                  mrelT + ((long)l * 6 + r1) * 8 * 64 * 64, nullptr, aux2,
                  N, 64, 64, 512, 64, 512, 64, 64 * 64, 64, 0, 8, 0);
            // fused softmax + gather + GELU (no atomics)
            hgt_gather_k<<<N, 256, 0, stream>>>(lgbuf, edge_index,
                                                csr_off + t * 8193, csr_ids + t * 65536,
                                                aux, aux2, aout, r0, r1);
            long wi = (long)l * 3 + t;
            mgemm_f(stream, aout, gaT + wi * 512 * 512, g_a_b + wi * 512, agg,
                    N, 512, 512, 512, 512, 512, 0);
            skip_ln_relu_k<<<N, 256, 0, stream>>>(agg, cur + (long)t * NH, nxt + (long)t * NH,
                                                  g_skip + (long)l * 3 + t,
                                                  g_ln_g + wi * 512, g_ln_b + wi * 512);
        }
        cur = nxt;
    }

    // ---------------- Classifier (cur == cur0) ------------------------------
    bf16* ci = S;
    bf16* c1out = QVbuf;
    concat3_k<<<(N * 1536 / 8) / 256, 256, 0, stream>>>(cur, cur + NH, cur + 2 * NH,
                                                        ci, N * 1536 / 8);
    mgemm(stream, ci, c1T, c1_b, c1out, N, 1536, 768, 1536, 1536, 768, 0, 0, 0, 0, 1, 1);
    head7_k<<<N / 4, 256, 0, stream>>>(c1out, c2_w, c2_b, (float*)d_out);
}

// Round 12
// 1975.738 us; speedup vs baseline: 1.2928x; 1.1662x over previous
//
#include <hip/hip_runtime.h>
#include <hip/hip_bf16.h>
#include <math.h>

#define N_NODES 8192
#define D_DLG   64
#define L_SEQ   128
#define H_DIM   512
#define N_HEADS 8
#define DHEAD   64
#define FF_DIM  2048
#define E_EDGES 32768

typedef __hip_bfloat16 bf16;
typedef __attribute__((ext_vector_type(8))) short short8;
typedef __attribute__((ext_vector_type(4))) float f32x4;

// ---------------- load/store helpers (bf16 <-> f32) -------------------------
__device__ __forceinline__ float bconv(unsigned short u) {
    return __uint_as_float((unsigned)u << 16);
}
__device__ __forceinline__ unsigned short fconv(float f) {
    bf16 h = __float2bfloat16(f);
    return *(unsigned short*)&h;
}
__device__ __forceinline__ float4 ld4(const float* p) { return *(const float4*)p; }
__device__ __forceinline__ float4 ld4(const bf16* p) {
    ushort4 u = *(const ushort4*)p;
    float4 v;
    v.x = bconv(u.x); v.y = bconv(u.y); v.z = bconv(u.z); v.w = bconv(u.w);
    return v;
}
__device__ __forceinline__ float ld1(const float* p) { return *p; }
__device__ __forceinline__ float ld1(const bf16* p) { return bconv(*(const unsigned short*)p); }
__device__ __forceinline__ void st1(float* p, float v) { *p = v; }
__device__ __forceinline__ void st1(bf16* p, float v) { *p = __float2bfloat16(v); }

__device__ __forceinline__ void gld_lds16(const bf16* g, bf16* l) {
    __builtin_amdgcn_global_load_lds(
        (const __attribute__((address_space(1))) void*)g,
        (__attribute__((address_space(3))) void*)l, 16, 0, 0);
}

// ---------------------------------------------------------------------------
// Weight pre-pass: f32 [z][K][N] -> bf16 [z][N][K] (transpose + convert).
// ---------------------------------------------------------------------------
__global__ __launch_bounds__(256) void transpose_k(const float* __restrict__ in,
                                                   bf16* __restrict__ out, int K, int N)
{
    __shared__ float tile[32][33];
    const long zoff = (long)blockIdx.z * K * N;
    const int n0 = blockIdx.x * 32, k0 = blockIdx.y * 32;
    const int tx = threadIdx.x, ty = threadIdx.y;
#pragma unroll
    for (int i = 0; i < 4; ++i)
        tile[ty + i * 8][tx] = in[zoff + (long)(k0 + ty + i * 8) * N + n0 + tx];
    __syncthreads();
#pragma unroll
    for (int i = 0; i < 4; ++i)
        st1(out + zoff + (long)(n0 + ty + i * 8) * K + k0 + tx, tile[tx][ty + i * 8]);
}

// ---------------------------------------------------------------------------
// MFMA GEMM: C = act(A @ Bt^T + bias). A bf16 [M][K] (lda), Bt bf16 [N][K]
// (ldb), C row-major (ldc). 64x64 tile, BK=64, 4 waves (2x2, 32x32 each).
// BK=64 doubles per-drain work (8 MFMA + 8 ds_read/wave) and halves drains.
// Bank swizzle: chunk c of row r lives in LDS slot c^(r&7) (inverse XOR on
// the per-lane GLOBAL source; LDS dest linear; read applies the same XOR).
// Bijective XCD tile swizzle. No inline asm. (R10-passing configuration.)
// ---------------------------------------------------------------------------
template <typename TC>
__global__ __launch_bounds__(256) void mgemm_k(
    const bf16* __restrict__ A, const bf16* __restrict__ Bt,
    const float* __restrict__ bias, TC* __restrict__ C,
    int M, int K, int Ncols, int lda, int ldb, int ldc,
    long sA, long sB, long sC, long sBias, int act)
{
    A  += (long)blockIdx.z * sA;
    Bt += (long)blockIdx.z * sB;
    C  += (long)blockIdx.z * sC;
    const float* bp = bias ? bias + (long)blockIdx.z * sBias : nullptr;

    __shared__ bf16 As[2][64 * 64];   // 8 KB per buffer
    __shared__ bf16 Bs[2][64 * 64];

    const int tid  = threadIdx.x;
    const int lane = tid & 63;
    const int wave = tid >> 6;
    const int wr   = wave >> 1;
    const int wc   = wave & 1;

    // ---- XCD-aware bijective tile swizzle (all launches have nwg % 8 == 0) -
    const int nwgx = gridDim.x;
    const int nwg  = nwgx * gridDim.y;
    int orig = blockIdx.y * nwgx + blockIdx.x;
    int wgid = ((nwg & 7) == 0) ? ((orig & 7) * (nwg >> 3) + (orig >> 3)) : orig;
    const int rowTile = (wgid / nwgx) * 64;
    const int colTile = (wgid % nwgx) * 64;

    // ---- staging: wave w writes rows w*8..w*8+7 (round 0) / +32 (round 1);
    //      lane l -> row w*8+(l>>3), LDS 16B-slot (l&7); the GLOBAL chunk is
    //      slot ^ (row&7) so that LDS slot s of row r holds chunk s^(r&7) ----
    const int sr0 = wave * 8 + (lane >> 3);
    const int sr1 = sr0 + 32;                       // same (row&7) as sr0
    const int sc  = ((lane & 7) ^ (sr0 & 7)) * 8;   // global k-chunk (elements)

    // ---- fragment read geometry --------------------------------------------
    const int frow = lane & 15;
    const int kgrp = lane >> 4;

    f32x4 acc[2][2];
#pragma unroll
    for (int i = 0; i < 2; ++i)
#pragma unroll
        for (int j = 0; j < 2; ++j) acc[i][j] = (f32x4){0.f, 0.f, 0.f, 0.f};

    const int nk = K >> 6;

#define STAGE(buf, kk)                                                          \
    do {                                                                        \
        gld_lds16(A  + (long)(rowTile + sr0) * lda + (kk) + sc, &As[buf][wave * 512]); \
        gld_lds16(A  + (long)(rowTile + sr1) * lda + (kk) + sc, &As[buf][2048 + wave * 512]); \
        gld_lds16(Bt + (long)(colTile + sr0) * ldb + (kk) + sc, &Bs[buf][wave * 512]); \
        gld_lds16(Bt + (long)(colTile + sr1) * ldb + (kk) + sc, &Bs[buf][2048 + wave * 512]); \
    } while (0)

    auto compute = [&](const bf16* as, const bf16* bs) {
        short8 av[2][2], bv[2][2];
#pragma unroll
        for (int mi = 0; mi < 2; ++mi) {
            int row = wr * 32 + mi * 16 + frow;
#pragma unroll
            for (int ks = 0; ks < 2; ++ks) {
                int slot = ((ks * 4 + kgrp) ^ (frow & 7)) * 8;
                av[mi][ks] = *(const short8*)(as + row * 64 + slot);
            }
        }
#pragma unroll
        for (int ni = 0; ni < 2; ++ni) {
            int row = wc * 32 + ni * 16 + frow;
#pragma unroll
            for (int ks = 0; ks < 2; ++ks) {
                int slot = ((ks * 4 + kgrp) ^ (frow & 7)) * 8;
                bv[ni][ks] = *(const short8*)(bs + row * 64 + slot);
            }
        }
#pragma unroll
        for (int ks = 0; ks < 2; ++ks)
#pragma unroll
            for (int mi = 0; mi < 2; ++mi)
#pragma unroll
                for (int ni = 0; ni < 2; ++ni)
                    acc[mi][ni] = __builtin_amdgcn_mfma_f32_16x16x32_bf16(
                        av[mi][ks], bv[ni][ks], acc[mi][ni], 0, 0, 0);
    };

    STAGE(0, 0);
    __syncthreads();

    for (int t = 0; t < nk; t += 2) {
        if (t + 1 < nk) STAGE(1, (t + 1) * 64);
        compute(As[0], Bs[0]);
        __syncthreads();
        if (t + 1 < nk) {
            if (t + 2 < nk) STAGE(0, (t + 2) * 64);
            compute(As[1], Bs[1]);
            __syncthreads();
        }
    }
#undef STAGE

#pragma unroll
    for (int ni = 0; ni < 2; ++ni) {
        int col = colTile + wc * 32 + ni * 16 + frow;
        if (col < Ncols) {
            float bb = bp ? bp[col] : 0.f;
#pragma unroll
            for (int mi = 0; mi < 2; ++mi) {
                long rbase = rowTile + wr * 32 + mi * 16 + kgrp * 4;
#pragma unroll
                for (int r = 0; r < 4; ++r) {
                    float v = acc[mi][ni][r] + bb;
                    if (act == 1) v = fmaxf(v, 0.f);
                    st1(C + (rbase + r) * (long)ldc + col, v);
                }
            }
        }
    }
}

// ---------------------------------------------------------------------------
// MFMA flash attention per (dialogue, head). 256 thr = 4 waves.
// ---------------------------------------------------------------------------
__global__ __launch_bounds__(256) void attn_mfma_k(const bf16* __restrict__ qkv,
                                                   bf16* __restrict__ o)
{
    __shared__ bf16 Pb[128 * 136];   // 34.8 KB, A-layout P
    __shared__ bf16 Vt[64 * 136];    // 17.4 KB, V^T [dh][l]
    __shared__ float pm[128][2];     // per-row partial max (per wave-col)
    __shared__ float ps[128][2];     // per-row partial sum

    const int d = blockIdx.x, h = blockIdx.y;
    const long base = (long)d * L_SEQ;
    const int tid  = threadIdx.x;
    const int lane = tid & 63;
    const int wave = tid >> 6;
    const int frow = lane & 15;
    const int kgrp = lane >> 4;
    const int wr = wave >> 1;        // S row-half
    const int wc = wave & 1;         // S col-half
    const float SC = 0.125f;

    // ---- V[l][dh] -> Vt[dh][l] (one-time scalar transpose) -----------------
    {
        int l = tid >> 1, dh0 = (tid & 1) * 32;
        const bf16* vp = qkv + (base + l) * 1536 + 1024 + h * 64 + dh0;
        unsigned short* vt = (unsigned short*)Vt;
#pragma unroll
        for (int j = 0; j < 4; ++j) {
            short8 v = *(const short8*)(vp + j * 8);
#pragma unroll
            for (int jj = 0; jj < 8; ++jj)
                vt[(dh0 + j * 8 + jj) * 136 + l] = (unsigned short)v[jj];
        }
    }

    // ---- Q,K fragments direct from global (no reuse -> no LDS) -------------
    short8 aq[4][2], bk[4][2];
#pragma unroll
    for (int mi = 0; mi < 4; ++mi) {
        long row = base + wr * 64 + mi * 16 + frow;
#pragma unroll
        for (int ks = 0; ks < 2; ++ks)
            aq[mi][ks] = *(const short8*)(qkv + row * 1536 + h * 64 + ks * 32 + kgrp * 8);
    }
#pragma unroll
    for (int ni = 0; ni < 4; ++ni) {
        long row = base + wc * 64 + ni * 16 + frow;
#pragma unroll
        for (int ks = 0; ks < 2; ++ks)
            bk[ni][ks] = *(const short8*)(qkv + row * 1536 + 512 + h * 64 + ks * 32 + kgrp * 8);
    }

    // ---- S = Q @ K^T (64x64 per wave) --------------------------------------
    f32x4 acc[4][4];
#pragma unroll
    for (int i = 0; i < 4; ++i)
#pragma unroll
        for (int j = 0; j < 4; ++j) acc[i][j] = (f32x4){0.f, 0.f, 0.f, 0.f};
#pragma unroll
    for (int ks = 0; ks < 2; ++ks)
#pragma unroll
        for (int mi = 0; mi < 4; ++mi)
#pragma unroll
            for (int ni = 0; ni < 4; ++ni)
                acc[mi][ni] = __builtin_amdgcn_mfma_f32_16x16x32_bf16(
                    aq[mi][ks], bk[ni][ks], acc[mi][ni], 0, 0, 0);

    // ---- per-wave row partials ---------------------------------------------
#pragma unroll
    for (int mi = 0; mi < 4; ++mi) {
#pragma unroll
        for (int r = 0; r < 4; ++r) {
            float mv = -1e30f;
#pragma unroll
            for (int ni = 0; ni < 4; ++ni) mv = fmaxf(mv, acc[mi][ni][r] * SC);
#pragma unroll
            for (int off = 1; off < 16; off <<= 1)
                mv = fmaxf(mv, __shfl_xor(mv, off, 64));
            float sv = 0.f;
#pragma unroll
            for (int ni = 0; ni < 4; ++ni) sv += __expf(acc[mi][ni][r] * SC - mv);
#pragma unroll
            for (int off = 1; off < 16; off <<= 1)
                sv += __shfl_xor(sv, off, 64);
            if (frow == 0) {
                int row = wr * 64 + mi * 16 + kgrp * 4 + r;
                pm[row][wc] = mv;
                ps[row][wc] = sv;
            }
        }
    }
    __syncthreads();

    // ---- merge halves, write P (bf16, A-layout) ----------------------------
    unsigned short* pb = (unsigned short*)Pb;
#pragma unroll
    for (int mi = 0; mi < 4; ++mi) {
#pragma unroll
        for (int r = 0; r < 4; ++r) {
            int row = wr * 64 + mi * 16 + kgrp * 4 + r;
            float m0 = pm[row][0], m1 = pm[row][1];
            float M = fmaxf(m0, m1);
            float Ssum = ps[row][0] * __expf(m0 - M) + ps[row][1] * __expf(m1 - M);
            float inv = 1.f / Ssum;
#pragma unroll
            for (int ni = 0; ni < 4; ++ni) {
                int col = wc * 64 + ni * 16 + frow;
                float p = __expf(acc[mi][ni][r] * SC - M) * inv;
                pb[row * 136 + col] = fconv(p);
            }
        }
    }
    __syncthreads();

    // ---- O = P @ V ----------------------------------------------------------
    f32x4 acc2[2][4];
#pragma unroll
    for (int i = 0; i < 2; ++i)
#pragma unroll
        for (int j = 0; j < 4; ++j) acc2[i][j] = (f32x4){0.f, 0.f, 0.f, 0.f};
#pragma unroll
    for (int ks = 0; ks < 4; ++ks) {
        short8 ap[2], bv[4];
#pragma unroll
        for (int mi = 0; mi < 2; ++mi)
            ap[mi] = *(const short8*)(Pb + (wave * 32 + mi * 16 + frow) * 136 + ks * 32 + kgrp * 8);
#pragma unroll
        for (int ni = 0; ni < 4; ++ni)
            bv[ni] = *(const short8*)(Vt + (ni * 16 + frow) * 136 + ks * 32 + kgrp * 8);
#pragma unroll
        for (int mi = 0; mi < 2; ++mi)
#pragma unroll
            for (int ni = 0; ni < 4; ++ni)
                acc2[mi][ni] = __builtin_amdgcn_mfma_f32_16x16x32_bf16(
                    ap[mi], bv[ni], acc2[mi][ni], 0, 0, 0);
    }
#pragma unroll
    for (int mi = 0; mi < 2; ++mi) {
#pragma unroll
        for (int ni = 0; ni < 4; ++ni) {
            int col = ni * 16 + frow;
            long rowb = wave * 32 + mi * 16 + kgrp * 4;
#pragma unroll
            for (int r = 0; r < 4; ++r)
                st1(o + (base + rowb + r) * 512 + h * 64 + col, acc2[mi][ni][r]);
        }
    }
}

// ---------------------------------------------------------------------------
// Classifier head: out[N,7] = A[N,768] @ W[768,7] + bias. Wave per row.
// ---------------------------------------------------------------------------
__global__ __launch_bounds__(256) void head7_k(
    const bf16* __restrict__ A, const float* __restrict__ W,
    const float* __restrict__ bias, float* __restrict__ out)
{
    const int wave = threadIdx.x >> 6, lane = threadIdx.x & 63;
    const long row = blockIdx.x * 4 + wave;
    const bf16* a = A + row * 768;
    float acc[7];
#pragma unroll
    for (int j = 0; j < 7; ++j) acc[j] = 0.f;
#pragma unroll
    for (int i = 0; i < 12; ++i) {
        int k = lane + i * 64;
        float av = ld1(a + k);
        const float* w = W + k * 7;
#pragma unroll
        for (int j = 0; j < 7; ++j) acc[j] = fmaf(av, w[j], acc[j]);
    }
#pragma unroll
    for (int j = 0; j < 7; ++j)
#pragma unroll
        for (int o = 32; o > 0; o >>= 1) acc[j] += __shfl_down(acc[j], o, 64);
    if (lane == 0) {
#pragma unroll
        for (int j = 0; j < 7; ++j) out[row * 7 + j] = acc[j] + bias[j];
    }
}

// ---------------------------------------------------------------------------
// xcat: vectorized x4 (4-aligned quads never straddle source regions).
// ---------------------------------------------------------------------------
__global__ void xcat_k(const float* __restrict__ x, const float* __restrict__ spk_emb,
                       const int* __restrict__ sidx, bf16* __restrict__ out, int n_quads)
{
    int q = blockIdx.x * 256 + threadIdx.x;
    if (q >= n_quads) return;
    int i = q * 4;
    int n = i / 576;
    int c = i - n * 576;
    const float* sp = (c < 512) ? (x + (long)n * 512 + c)
                                : (spk_emb + (long)sidx[n] * 64 + (c - 512));
    float4 v = *(const float4*)sp;
    ushort4 u;
    u.x = fconv(v.x); u.y = fconv(v.y); u.z = fconv(v.z); u.w = fconv(v.w);
    *(ushort4*)(out + i) = u;
}

// ---------------------------------------------------------------------------
// add_ln: pair-loads; residual r is bf16.
// ---------------------------------------------------------------------------
__global__ __launch_bounds__(256) void add_ln_k(bf16* __restrict__ h, const bf16* __restrict__ r,
                                                const float* __restrict__ g, const float* __restrict__ b)
{
    const int row = blockIdx.x;
    const int tid = threadIdx.x;
    const long base = (long)row * 512 + tid * 2;
    ushort2 hu = *(const ushort2*)(h + base);
    ushort2 ru = *(const ushort2*)(r + base);
    float x0 = bconv(hu.x) + bconv(ru.x);
    float x1 = bconv(hu.y) + bconv(ru.y);
    float s = x0 + x1;
    float q = x0 * x0 + x1 * x1;
#pragma unroll
    for (int o = 32; o > 0; o >>= 1) { s += __shfl_down(s, o, 64); q += __shfl_down(q, o, 64); }
    __shared__ float ls[4], lq[4];
    if ((tid & 63) == 0) { ls[tid >> 6] = s; lq[tid >> 6] = q; }
    __syncthreads();
    float S = ls[0] + ls[1] + ls[2] + ls[3];
    float Q = lq[0] + lq[1] + lq[2] + lq[3];
    float mu = S * (1.f / 512.f);
    float var = Q * (1.f / 512.f) - mu * mu;
    float inv = rsqrtf(fmaxf(var, 0.f) + 1e-5f);
    float2 gv = *(const float2*)(g + tid * 2);
    float2 bv = *(const float2*)(b + tid * 2);
    ushort2 o2;
    o2.x = fconv((x0 - mu) * inv * gv.x + bv.x);
    o2.y = fconv((x1 - mu) * inv * gv.y + bv.y);
    *(ushort2*)(h + base) = o2;
}

__global__ __launch_bounds__(256) void skip_ln_relu_k(
    const float* __restrict__ outp, const bf16* __restrict__ curp, bf16* __restrict__ dst,
    const float* __restrict__ gskip, const float* __restrict__ g, const float* __restrict__ b)
{
    const int row = blockIdx.x;
    const int tid = threadIdx.x;
    const float beta = 1.f / (1.f + __expf(-gskip[0]));
    const long base = (long)row * 512 + tid * 2;
    float2 ov = *(const float2*)(outp + base);
    ushort2 cu = *(const ushort2*)(curp + base);
    float x0 = beta * ov.x + (1.f - beta) * bconv(cu.x);
    float x1 = beta * ov.y + (1.f - beta) * bconv(cu.y);
    float s = x0 + x1;
    float q = x0 * x0 + x1 * x1;
#pragma unroll
    for (int o = 32; o > 0; o >>= 1) { s += __shfl_down(s, o, 64); q += __shfl_down(q, o, 64); }
    __shared__ float ls[4], lq[4];
    if ((tid & 63) == 0) { ls[tid >> 6] = s; lq[tid >> 6] = q; }
    __syncthreads();
    float S = ls[0] + ls[1] + ls[2] + ls[3];
    float Q = lq[0] + lq[1] + lq[2] + lq[3];
    float mu = S * (1.f / 512.f);
    float var = Q * (1.f / 512.f) - mu * mu;
    float inv = rsqrtf(fmaxf(var, 0.f) + 1e-5f);
    float2 gv = *(const float2*)(g + tid * 2);
    float2 bv = *(const float2*)(b + tid * 2);
    ushort2 o2;
    o2.x = fconv(fmaxf((x0 - mu) * inv * gv.x + bv.x, 0.f));
    o2.y = fconv(fmaxf((x1 - mu) * inv * gv.y + bv.y, 0.f));
    *(ushort2*)(dst + base) = o2;
}

// ---------------------------------------------------------------------------
// Edge logits, CSR(dst)-ordered: one dispatch per dst-type group handles both
// incoming edge types. Position p walks dst-sorted order -> Q-row reads are
// near-sequential (L2-resident) instead of random+XCD-duplicated. Output is
// dst-sorted lg2[p][h], read sequentially by hgt_gather_k.
// ---------------------------------------------------------------------------
__global__ void edge_logit2_k(float* __restrict__ lg2, const bf16* __restrict__ qq,
                              const bf16* __restrict__ kj0, const bf16* __restrict__ kj1,
                              const int* __restrict__ ei, const int* __restrict__ ids,
                              const float* __restrict__ prel0, const float* __restrict__ prel1,
                              int r0, int r1)
{
    int tid = blockIdx.x * 256 + threadIdx.x;
    int p = tid >> 3;                  // position within group, < 2*E_EDGES
    int h = tid & 7;
    int idx = ids[p];
    int gi = idx >> 15, e = idx & 32767;
    int r = gi ? r1 : r0;
    int dst = ei[((long)r * 2 + 1) * E_EDGES + e];
    int src = ei[((long)r * 2 + 0) * E_EDGES + e];
    const bf16* qp = qq + (long)dst * 512 + h * 64;
    const bf16* kp = (gi ? kj1 : kj0) + (long)src * 512 + h * 64;
    float acc = 0.f;
#pragma unroll
    for (int i = 0; i < 64; i += 4) {
        float4 a = ld4(qp + i);
        float4 c = ld4(kp + i);
        acc = fmaf(a.x, c.x, acc); acc = fmaf(a.y, c.y, acc);
        acc = fmaf(a.z, c.z, acc); acc = fmaf(a.w, c.w, acc);
    }
    lg2[(long)p * 8 + h] = acc * (gi ? prel1 : prel0)[h] * 0.125f;
}

// ---------------------------------------------------------------------------
// CSR build over dst: per dst-type group g (3 groups, 2 edge types each,
// 65536 edges -> 8192 dst nodes). ids pack: (gi<<15) | e.
// ---------------------------------------------------------------------------
__global__ void csr_zero_k(int* __restrict__ off, int* __restrict__ cur)
{
    int i = blockIdx.x * 256 + threadIdx.x;
    if (i < 3 * 8193) off[i] = 0;
    if (i < 3 * 8192) cur[i] = 0;
}

__global__ void csr_count_k(const int* __restrict__ ei, int* __restrict__ off)
{
    int tid = blockIdx.x * 256 + threadIdx.x;       // 3*2*E threads
    int g   = tid >> 16;                             // / 65536
    int rem = tid & 65535;
    int gi  = rem >> 15;
    int e   = rem & (E_EDGES - 1);
    const int GR[6] = {1, 3, 0, 5, 2, 4};
    int r   = GR[g * 2 + gi];
    int dst = ei[((long)r * 2 + 1) * E_EDGES + e];
    atomicAdd(&off[g * 8193 + dst + 1], 1);
}

__global__ __launch_bounds__(256) void csr_scan_k(int* __restrict__ off, int* __restrict__ cur)
{
    const int g = blockIdx.x, t = threadIdx.x;
    int* o = off + g * 8193;
    int v[32];
    int s = 0;
#pragma unroll
    for (int j = 0; j < 32; ++j) { v[j] = o[t * 32 + j + 1]; s += v[j]; }
    __shared__ int ps[256];
    ps[t] = s;
    __syncthreads();
    for (int d = 1; d < 256; d <<= 1) {
        int x = 0;
        if (t >= d) x = ps[t - d];
        __syncthreads();
        if (t >= d) ps[t] += x;
        __syncthreads();
    }
    int run = (t ? ps[t - 1] : 0);
#pragma unroll
    for (int j = 0; j < 32; ++j) {
        cur[g * 8192 + t * 32 + j] = run;   // exclusive prefix = fill cursor
        run += v[j];
        o[t * 32 + j + 1] = run;            // inclusive -> off[d+1]
    }
}

__global__ void csr_fill_k(const int* __restrict__ ei, int* __restrict__ cur,
                           int* __restrict__ ids)
{
    int tid = blockIdx.x * 256 + threadIdx.x;
    int g   = tid >> 16;
    int rem = tid & 65535;
    int gi  = rem >> 15;
    int e   = rem & (E_EDGES - 1);
    const int GR[6] = {1, 3, 0, 5, 2, 4};
    int r   = GR[g * 2 + gi];
    int dst = ei[((long)r * 2 + 1) * E_EDGES + e];
    int p = atomicAdd(&cur[g * 8192 + dst], 1);
    ids[g * 65536 + p] = (gi << 15) | e;
}

// ---------------------------------------------------------------------------
// Fused HGT aggregation: one block per dst node; online segment softmax +
// alpha-weighted gather of mj[src] + GELU. No global atomics. Logits arrive
// dst-sorted in lg2 -> staging is a sequential coalesced read.
// ---------------------------------------------------------------------------
__global__ __launch_bounds__(256) void hgt_gather_k(
    const float* __restrict__ lg2, const int* __restrict__ ei,
    const int* __restrict__ off, const int* __restrict__ ids,
    const bf16* __restrict__ vt0, const bf16* __restrict__ vt1,
    bf16* __restrict__ aout, int r0, int r1)
{
    const int n = blockIdx.x, tid = threadIdx.x;
    const int beg = off[n], end = off[n + 1];

    __shared__ int   sh_idx[256];
    __shared__ float sh_al[256 * 8];    // logits, then unnormalized alphas
    __shared__ float pm[64];
    __shared__ float mrun[8], srun[8], resc[8];

    if (tid < 8) { mrun[tid] = -1e30f; srun[tid] = 0.f; }
    const int c0 = tid * 2;             // two consecutive channels, same head
    const int h  = tid >> 5;
    float a0 = 0.f, a1 = 0.f;
    __syncthreads();

    for (int t0 = beg; t0 < end; t0 += 256) {
        const int cnt = min(256, end - t0);
        if (tid < cnt) sh_idx[tid] = ids[t0 + tid];
        __syncthreads();
        // stage logits for this tile (sequential, dst-sorted layout)
        {
            const float* lgp = lg2 + (long)t0 * 8;
            for (int i = tid; i < cnt * 8; i += 256)
                sh_al[i] = lgp[i];
        }
        __syncthreads();
        // tile max per head (8 slots x 8 heads)
        if (tid < 64) {
            int hh = tid & 7, sl = tid >> 3;
            float m = -1e30f;
            for (int i = sl; i < cnt; i += 8) m = fmaxf(m, sh_al[i * 8 + hh]);
            pm[tid] = m;
        }
        __syncthreads();
        if (tid < 8) {
            float m = pm[tid];
#pragma unroll
            for (int sl = 1; sl < 8; ++sl) m = fmaxf(m, pm[sl * 8 + tid]);
            float nm = fmaxf(mrun[tid], m);
            resc[tid] = __expf(mrun[tid] - nm);
            mrun[tid] = nm;
        }
        __syncthreads();
        // rescale accumulators; unnormalized alphas in place
        float rs = resc[h];
        a0 *= rs; a1 *= rs;
        for (int i = tid; i < cnt * 8; i += 256)
            sh_al[i] = __expf(sh_al[i] - mrun[i & 7]);
        __syncthreads();
        // tile sum per head
        if (tid < 64) {
            int hh = tid & 7, sl = tid >> 3;
            float s = 0.f;
            for (int i = sl; i < cnt; i += 8) s += sh_al[i * 8 + hh];
            pm[tid] = s;
        }
        __syncthreads();
        if (tid < 8) {
            float s = 0.f;
#pragma unroll
            for (int sl = 0; sl < 8; ++sl) s += pm[sl * 8 + tid];
            srun[tid] = srun[tid] * resc[tid] + s;
        }
        // accumulate alpha * mj[src] (coalesced 4B/lane rows of mj)
        for (int i = 0; i < cnt; ++i) {
            int idx = sh_idx[i];
            int gi = idx >> 15, e = idx & 32767;
            int r = gi ? r1 : r0;
            float al = sh_al[i * 8 + h];
            int src = ei[((long)r * 2) * E_EDGES + e];
            const bf16* v = (gi ? vt1 : vt0) + (long)src * 512 + c0;
            ushort2 u = *(const ushort2*)v;
            a0 = fmaf(al, bconv(u.x), a0);
            a1 = fmaf(al, bconv(u.y), a1);
        }
        __syncthreads();
    }
    float iv = 1.f / (srun[h] + 1e-9f);
    a0 *= iv; a1 *= iv;
    // fused GELU (tanh approx), bf16 store
    float t0v = tanhf(0.79788456080286535588f * (a0 + 0.044715f * a0 * a0 * a0));
    float t1v = tanhf(0.79788456080286535588f * (a1 + 0.044715f * a1 * a1 * a1));
    unsigned short o0 = fconv(0.5f * a0 * (1.f + t0v));
    unsigned short o1 = fconv(0.5f * a1 * (1.f + t1v));
    *(ushort2*)(aout + (long)n * 512 + c0) = make_ushort2(o0, o1);
}

// ---------------------------------------------------------------------------
// concat3: vectorized x8 (512-boundaries are 8-aligned; bit-identical).
// ---------------------------------------------------------------------------
__global__ void concat3_k(const bf16* __restrict__ a, const bf16* __restrict__ b,
                          const bf16* __restrict__ c, bf16* __restrict__ out, int n_oct)
{
    int q = blockIdx.x * 256 + threadIdx.x;
    if (q >= n_oct) return;
    int i = q * 8;
    int n = i / 1536;
    int cc = i - n * 1536;
    const bf16* sp = (cc < 512) ? a : (cc < 1024 ? b : c);
    *(short8*)(out + i) = *(const short8*)(sp + (long)n * 512 + (cc & 511));
}

// ---------------------------------------------------------------------------
static inline void convT(hipStream_t st, const float* in, bf16* out, int K, int N, int z)
{
    dim3 g(N / 32, K / 32, z), b(32, 8);
    transpose_k<<<g, b, 0, st>>>(in, out, K, N);
}
static inline void mgemm(hipStream_t st, const bf16* A, const bf16* Bt, const float* bias,
                         bf16* C, int M, int K, int Ncols, int lda, int ldb, int ldc,
                         long sA, long sB, long sC, long sBias, int z, int act)
{
    dim3 g((Ncols + 63) / 64, M / 64, z);
    mgemm_k<bf16><<<g, 256, 0, st>>>(A, Bt, bias, C, M, K, Ncols, lda, ldb, ldc,
                                     sA, sB, sC, sBias, act);
}
static inline void mgemm_f(hipStream_t st, const bf16* A, const bf16* Bt, const float* bias,
                           float* C, int M, int K, int Ncols, int lda, int ldb, int ldc, int act)
{
    dim3 g((Ncols + 63) / 64, M / 64, 1);
    mgemm_k<float><<<g, 256, 0, st>>>(A, Bt, bias, C, M, K, Ncols, lda, ldb, ldc,
                                      0, 0, 0, 0, act);
}

extern "C" void kernel_launch(void* const* d_in, const int* in_sizes, int n_in,
                              void* d_out, int out_size, void* d_ws, size_t ws_size,
                              hipStream_t stream)
{
    const float* x_audio = (const float*)d_in[0];
    const float* x_text  = (const float*)d_in[1];
    const float* x_video = (const float*)d_in[2];
    const float* spk_emb = (const float*)d_in[3];
    const float* proj_w  = (const float*)d_in[4];
    const float* proj_b  = (const float*)d_in[5];
    const float* t_qkv_w = (const float*)d_in[6];
    const float* t_qkv_b = (const float*)d_in[7];
    const float* t_out_w = (const float*)d_in[8];
    const float* t_out_b = (const float*)d_in[9];
    const float* t_ff1_w = (const float*)d_in[10];
    const float* t_ff1_b = (const float*)d_in[11];
    const float* t_ff2_w = (const float*)d_in[12];
    const float* t_ff2_b = (const float*)d_in[13];
    const float* t_ln1_g = (const float*)d_in[14];
    const float* t_ln1_b = (const float*)d_in[15];
    const float* t_ln2_g = (const float*)d_in[16];
    const float* t_ln2_b = (const float*)d_in[17];
    const float* g_k_w   = (const float*)d_in[18];
    const float* g_k_b   = (const float*)d_in[19];
    const float* g_q_w   = (const float*)d_in[20];
    const float* g_q_b   = (const float*)d_in[21];
    const float* g_v_w   = (const float*)d_in[22];
    const float* g_v_b   = (const float*)d_in[23];
    const float* g_a_w   = (const float*)d_in[24];
    const float* g_a_b   = (const float*)d_in[25];
    const float* g_skip  = (const float*)d_in[26];
    const float* g_arel  = (const float*)d_in[27];
    const float* g_mrel  = (const float*)d_in[28];
    const float* g_prel  = (const float*)d_in[29];
    const float* g_ln_g  = (const float*)d_in[30];
    const float* g_ln_b  = (const float*)d_in[31];
    const float* c1_w    = (const float*)d_in[32];
    const float* c1_b    = (const float*)d_in[33];
    const float* c2_w    = (const float*)d_in[34];
    const float* c2_b    = (const float*)d_in[35];
    const int* speaker_idx = (const int*)d_in[36];
    const int* edge_index  = (const int*)d_in[38];

    const int N = N_NODES;
    const long NH = (long)N_NODES * H_DIM;

    // ---- bf16-transposed weight region (~56 MB) ----------------------------
    bf16* Wbf = (bf16*)d_ws;
    long off = 0;
    bf16* projT = Wbf + off; off += 3L * 512 * 576;
    bf16* qkvT  = Wbf + off; off += 6L * 1536 * 512;
    bf16* outT  = Wbf + off; off += 6L * 512 * 512;
    bf16* ff1T  = Wbf + off; off += 6L * 2048 * 512;
    bf16* ff2T  = Wbf + off; off += 6L * 512 * 2048;
    bf16* gkT   = Wbf + off; off += 6L * 512 * 512;
    bf16* gqT   = Wbf + off; off += 6L * 512 * 512;
    bf16* gvT   = Wbf + off; off += 6L * 512 * 512;
    bf16* gaT   = Wbf + off; off += 6L * 512 * 512;
    bf16* arelT = Wbf + off; off += 96L * 64 * 64;
    bf16* mrelT = Wbf + off; off += 96L * 64 * 64;
    bf16* c1T   = Wbf + off; off += 768L * 1536;
    off += 4096;  // slack

    // ---- activation workspace (unchanged footprint) ------------------------
    bf16* cur0  = Wbf + off;
    bf16* Kbuf  = cur0 + 3 * NH;
    bf16* QVbuf = Kbuf + 3 * NH;
    bf16* S     = QVbuf + 3 * NH;          // N*2048 scratch
    bf16* aux   = S + (long)N * 2048;      // 2*NH
    bf16* aux2  = aux + NH;

    bf16* xin   = S;
    bf16* qkvb  = S;
    bf16* attno = S + (long)N * 1536;
    bf16* outp  = S;
    bf16* ffb   = S;
    float* agg   = (float*)S;                               // 16.8 MB
    float* lgbuf = agg + NH;                                // 6.3 MB dst-sorted logits
    int* csr_off = (int*)(lgbuf + 3L * 2 * E_EDGES * 8);    // 3 x 8193
    int* csr_cur = csr_off + 3 * 8193;                      // 3 x 8192
    int* csr_ids = csr_cur + 3 * 8192;                      // 3 x 65536
    bf16* aout   = (bf16*)(csr_ids + 3 * 65536);            // 8.4 MB

    static const int META_S[6] = {0, 1, 0, 2, 1, 2};
    static const int GROUPS[3][2] = {{1, 3}, {0, 5}, {2, 4}};
    const float* xs[3] = {x_audio, x_text, x_video};

    // ---------------- Weight pre-pass ---------------------------------------
    convT(stream, proj_w,  projT, 576, 512, 3);
    convT(stream, t_qkv_w, qkvT,  512, 1536, 6);
    convT(stream, t_out_w, outT,  512, 512, 6);
    convT(stream, t_ff1_w, ff1T,  512, 2048, 6);
    convT(stream, t_ff2_w, ff2T,  2048, 512, 6);
    convT(stream, g_k_w,   gkT,   512, 512, 6);
    convT(stream, g_q_w,   gqT,   512, 512, 6);
    convT(stream, g_v_w,   gvT,   512, 512, 6);
    convT(stream, g_a_w,   gaT,   512, 512, 6);
    convT(stream, g_arel,  arelT, 64, 64, 96);
    convT(stream, g_mrel,  mrelT, 64, 64, 96);
    convT(stream, c1_w,    c1T,   1536, 768, 1);

    // ---------------- Stage 1+2: projection + transformer encoder ----------
    for (int t = 0; t < 3; ++t) {
        bf16* h = cur0 + (long)t * NH;
        xcat_k<<<(N * 576 / 4) / 256, 256, 0, stream>>>(xs[t], spk_emb, speaker_idx,
                                                        xin, N * 576 / 4);
        mgemm(stream, xin, projT + (long)t * 512 * 576, proj_b + (long)t * 512, h,
              N, 576, 512, 576, 576, 512, 0, 0, 0, 0, 1, 0);
        for (int l = 0; l < 2; ++l) {
            long wi = (long)t * 2 + l;
            mgemm(stream, h, qkvT + wi * 1536 * 512, t_qkv_b + wi * 1536, qkvb,
                  N, 512, 1536, 512, 512, 1536, 0, 0, 0, 0, 1, 0);
            attn_mfma_k<<<dim3(D_DLG, N_HEADS), 256, 0, stream>>>(qkvb, attno);
            mgemm(stream, attno, outT + wi * 512 * 512, t_out_b + wi * 512, outp,
                  N, 512, 512, 512, 512, 512, 0, 0, 0, 0, 1, 0);
            add_ln_k<<<N, 256, 0, stream>>>(h, outp, t_ln1_g + wi * 512, t_ln1_b + wi * 512);
            mgemm(stream, h, ff1T + wi * 2048 * 512, t_ff1_b + wi * 2048, ffb,
                  N, 512, 2048, 512, 512, 2048, 0, 0, 0, 0, 1, 1);
            mgemm(stream, ffb, ff2T + wi * 512 * 2048, t_ff2_b + wi * 512, aux,
                  N, 2048, 512, 2048, 2048, 512, 0, 0, 0, 0, 1, 0);
            add_ln_k<<<N, 256, 0, stream>>>(h, aux, t_ln2_g + wi * 512, t_ln2_b + wi * 512);
        }
    }

    // ---------------- CSR build (once; edge_index is layer-invariant) -------
    csr_zero_k<<<(3 * 8193 + 255) / 256, 256, 0, stream>>>(csr_off, csr_cur);
    csr_count_k<<<(3 * 2 * E_EDGES) / 256, 256, 0, stream>>>(edge_index, csr_off);
    csr_scan_k<<<3, 256, 0, stream>>>(csr_off, csr_cur);
    csr_fill_k<<<(3 * 2 * E_EDGES) / 256, 256, 0, stream>>>(edge_index, csr_cur, csr_ids);

    // ---------------- Stage 3: HGT layers ----------------------------------
    bf16* cur = cur0;
    for (int l = 0; l < 2; ++l) {
        bf16* Kr  = (l == 0) ? Kbuf : cur0;
        bf16* QVr = QVbuf;
        bf16* nxt = Kr;
        // z-batched K and Q projections over the 3 node types
        mgemm(stream, cur, gkT + (long)l * 3 * 512 * 512, g_k_b + (long)l * 3 * 512, Kr,
              N, 512, 512, 512, 512, 512, NH, 512L * 512, NH, 512, 3, 0);
        mgemm(stream, cur, gqT + (long)l * 3 * 512 * 512, g_q_b + (long)l * 3 * 512, QVr,
              N, 512, 512, 512, 512, 512, NH, 512L * 512, NH, 512, 3, 0);
        // per dst-group: kj for both incoming edge types, then CSR-ordered logits
        for (int t = 0; t < 3; ++t) {
            int r0 = GROUPS[t][0], r1 = GROUPS[t][1];
            mgemm(stream, Kr + (long)META_S[r0] * NH,
                  arelT + ((long)l * 6 + r0) * 8 * 64 * 64, nullptr, aux,
                  N, 64, 64, 512, 64, 512, 64, 64 * 64, 64, 0, 8, 0);
            mgemm(stream, Kr + (long)META_S[r1] * NH,
                  arelT + ((long)l * 6 + r1) * 8 * 64 * 64, nullptr, aux2,
                  N, 64, 64, 512, 64, 512, 64, 64 * 64, 64, 0, 8, 0);
            edge_logit2_k<<<(2 * E_EDGES * 8) / 256, 256, 0, stream>>>(
                lgbuf + (long)t * 2 * E_EDGES * 8, QVr + (long)t * NH, aux, aux2,
                edge_index, csr_ids + t * 65536,
                g_prel + ((long)l * 6 + r0) * 8, g_prel + ((long)l * 6 + r1) * 8, r0, r1);
        }
        // z-batched V projection (after edge logits consumed Q from QVr)
        mgemm(stream, cur, gvT + (long)l * 3 * 512 * 512, g_v_b + (long)l * 3 * 512, QVr,
              N, 512, 512, 512, 512, 512, NH, 512L * 512, NH, 512, 3, 0);
        for (int t = 0; t < 3; ++t) {
            int r0 = GROUPS[t][0], r1 = GROUPS[t][1];
            // mj = V @ mrel for the two incoming edge types
            mgemm(stream, QVr + (long)META_S[r0] * NH,
                  mrelT + ((long)l * 6 + r0) * 8 * 64 * 64, nullptr, aux,
                  N, 64, 64, 512, 64, 512, 64, 64 * 64, 64, 0, 8, 0);
            mgemm(stream, QVr + (long)META_S[r1] * NH,
                  mrelT + ((long)l * 6 + r1) * 8 * 64 * 64, nullptr, aux2,
                  N, 64, 64, 512, 64, 512, 64, 64 * 64, 64, 0, 8, 0);
            // fused softmax + gather + GELU (no atomics)
            hgt_gather_k<<<N, 256, 0, stream>>>(lgbuf + (long)t * 2 * E_EDGES * 8,
                                                edge_index,
                                                csr_off + t * 8193, csr_ids + t * 65536,
                                                aux, aux2, aout, r0, r1);
            long wi = (long)l * 3 + t;
            mgemm_f(stream, aout, gaT + wi * 512 * 512, g_a_b + wi * 512, agg,
                    N, 512, 512, 512, 512, 512, 0);
            skip_ln_relu_k<<<N, 256, 0, stream>>>(agg, cur + (long)t * NH, nxt + (long)t * NH,
                                                  g_skip + (long)l * 3 + t,
                                                  g_ln_g + wi * 512, g_ln_b + wi * 512);
        }
        cur = nxt;
    }

    // ---------------- Classifier (cur == cur0) ------------------------------
    bf16* ci = S;
    bf16* c1out = QVbuf;
    concat3_k<<<(N * 1536 / 8) / 256, 256, 0, stream>>>(cur, cur + NH, cur + 2 * NH,
                                                        ci, N * 1536 / 8);
    mgemm(stream, ci, c1T, c1_b, c1out, N, 1536, 768, 1536, 1536, 768, 0, 0, 0, 0, 1, 1);
    head7_k<<<N / 4, 256, 0, stream>>>(c1out, c2_w, c2_b, (float*)d_out);
}

// Round 13
// 1961.502 us; speedup vs baseline: 1.3021x; 1.0073x over previous
//
#include <hip/hip_runtime.h>
#include <hip/hip_bf16.h>
#include <math.h>

#define N_NODES 8192
#define D_DLG   64
#define L_SEQ   128
#define H_DIM   512
#define N_HEADS 8
#define DHEAD   64
#define FF_DIM  2048
#define E_EDGES 32768

typedef __hip_bfloat16 bf16;
typedef __attribute__((ext_vector_type(8))) short short8;
typedef __attribute__((ext_vector_type(4))) float f32x4;

// ---------------- load/store helpers (bf16 <-> f32) -------------------------
__device__ __forceinline__ float bconv(unsigned short u) {
    return __uint_as_float((unsigned)u << 16);
}
__device__ __forceinline__ unsigned short fconv(float f) {
    bf16 h = __float2bfloat16(f);
    return *(unsigned short*)&h;
}
__device__ __forceinline__ float4 ld4(const float* p) { return *(const float4*)p; }
__device__ __forceinline__ float4 ld4(const bf16* p) {
    ushort4 u = *(const ushort4*)p;
    float4 v;
    v.x = bconv(u.x); v.y = bconv(u.y); v.z = bconv(u.z); v.w = bconv(u.w);
    return v;
}
__device__ __forceinline__ float ld1(const float* p) { return *p; }
__device__ __forceinline__ float ld1(const bf16* p) { return bconv(*(const unsigned short*)p); }
__device__ __forceinline__ void st1(float* p, float v) { *p = v; }
__device__ __forceinline__ void st1(bf16* p, float v) { *p = __float2bfloat16(v); }

__device__ __forceinline__ void gld_lds16(const bf16* g, bf16* l) {
    __builtin_amdgcn_global_load_lds(
        (const __attribute__((address_space(1))) void*)g,
        (__attribute__((address_space(3))) void*)l, 16, 0, 0);
}

// bijective XCD chunk swizzle for a flat block id (requires n % 8 == 0)
__device__ __forceinline__ int xcd_swz(int orig, int n) {
    return ((n & 7) == 0) ? ((orig & 7) * (n >> 3) + (orig >> 3)) : orig;
}

// ---------------------------------------------------------------------------
// Weight pre-pass: f32 [z][K][N] -> bf16 [z][N][K] (transpose + convert).
// ---------------------------------------------------------------------------
__global__ __launch_bounds__(256) void transpose_k(const float* __restrict__ in,
                                                   bf16* __restrict__ out, int K, int N)
{
    __shared__ float tile[32][33];
    const long zoff = (long)blockIdx.z * K * N;
    const int n0 = blockIdx.x * 32, k0 = blockIdx.y * 32;
    const int tx = threadIdx.x, ty = threadIdx.y;
#pragma unroll
    for (int i = 0; i < 4; ++i)
        tile[ty + i * 8][tx] = in[zoff + (long)(k0 + ty + i * 8) * N + n0 + tx];
    __syncthreads();
#pragma unroll
    for (int i = 0; i < 4; ++i)
        st1(out + zoff + (long)(n0 + ty + i * 8) * K + k0 + tx, tile[tx][ty + i * 8]);
}

// ---------------------------------------------------------------------------
// MFMA GEMM: C = act(A @ Bt^T + bias). A bf16 [M][K] (lda), Bt bf16 [N][K]
// (ldb), C row-major (ldc). 64x64 tile, BK=64, 4 waves (2x2, 32x32 each).
// BK=64 doubles per-drain work (8 MFMA + 8 ds_read/wave) and halves drains.
// Bank swizzle: chunk c of row r lives in LDS slot c^(r&7) (inverse XOR on
// the per-lane GLOBAL source; LDS dest linear; read applies the same XOR).
// Bijective XCD tile swizzle. No inline asm. (R10/R12-passing config.)
// ---------------------------------------------------------------------------
template <typename TC>
__global__ __launch_bounds__(256) void mgemm_k(
    const bf16* __restrict__ A, const bf16* __restrict__ Bt,
    const float* __restrict__ bias, TC* __restrict__ C,
    int M, int K, int Ncols, int lda, int ldb, int ldc,
    long sA, long sB, long sC, long sBias, int act)
{
    A  += (long)blockIdx.z * sA;
    Bt += (long)blockIdx.z * sB;
    C  += (long)blockIdx.z * sC;
    const float* bp = bias ? bias + (long)blockIdx.z * sBias : nullptr;

    __shared__ bf16 As[2][64 * 64];   // 8 KB per buffer
    __shared__ bf16 Bs[2][64 * 64];

    const int tid  = threadIdx.x;
    const int lane = tid & 63;
    const int wave = tid >> 6;
    const int wr   = wave >> 1;
    const int wc   = wave & 1;

    // ---- XCD-aware bijective tile swizzle ----------------------------------
    const int nwgx = gridDim.x;
    const int nwg  = nwgx * gridDim.y;
    int orig = blockIdx.y * nwgx + blockIdx.x;
    int wgid = xcd_swz(orig, nwg);
    const int rowTile = (wgid / nwgx) * 64;
    const int colTile = (wgid % nwgx) * 64;

    // ---- staging: wave w writes rows w*8..w*8+7 (round 0) / +32 (round 1);
    //      lane l -> row w*8+(l>>3), LDS 16B-slot (l&7); the GLOBAL chunk is
    //      slot ^ (row&7) so that LDS slot s of row r holds chunk s^(r&7) ----
    const int sr0 = wave * 8 + (lane >> 3);
    const int sr1 = sr0 + 32;                       // same (row&7) as sr0
    const int sc  = ((lane & 7) ^ (sr0 & 7)) * 8;   // global k-chunk (elements)

    // ---- fragment read geometry --------------------------------------------
    const int frow = lane & 15;
    const int kgrp = lane >> 4;

    f32x4 acc[2][2];
#pragma unroll
    for (int i = 0; i < 2; ++i)
#pragma unroll
        for (int j = 0; j < 2; ++j) acc[i][j] = (f32x4){0.f, 0.f, 0.f, 0.f};

    const int nk = K >> 6;

#define STAGE(buf, kk)                                                          \
    do {                                                                        \
        gld_lds16(A  + (long)(rowTile + sr0) * lda + (kk) + sc, &As[buf][wave * 512]); \
        gld_lds16(A  + (long)(rowTile + sr1) * lda + (kk) + sc, &As[buf][2048 + wave * 512]); \
        gld_lds16(Bt + (long)(colTile + sr0) * ldb + (kk) + sc, &Bs[buf][wave * 512]); \
        gld_lds16(Bt + (long)(colTile + sr1) * ldb + (kk) + sc, &Bs[buf][2048 + wave * 512]); \
    } while (0)

    auto compute = [&](const bf16* as, const bf16* bs) {
        short8 av[2][2], bv[2][2];
#pragma unroll
        for (int mi = 0; mi < 2; ++mi) {
            int row = wr * 32 + mi * 16 + frow;
#pragma unroll
            for (int ks = 0; ks < 2; ++ks) {
                int slot = ((ks * 4 + kgrp) ^ (frow & 7)) * 8;
                av[mi][ks] = *(const short8*)(as + row * 64 + slot);
            }
        }
#pragma unroll
        for (int ni = 0; ni < 2; ++ni) {
            int row = wc * 32 + ni * 16 + frow;
#pragma unroll
            for (int ks = 0; ks < 2; ++ks) {
                int slot = ((ks * 4 + kgrp) ^ (frow & 7)) * 8;
                bv[ni][ks] = *(const short8*)(bs + row * 64 + slot);
            }
        }
#pragma unroll
        for (int ks = 0; ks < 2; ++ks)
#pragma unroll
            for (int mi = 0; mi < 2; ++mi)
#pragma unroll
                for (int ni = 0; ni < 2; ++ni)
                    acc[mi][ni] = __builtin_amdgcn_mfma_f32_16x16x32_bf16(
                        av[mi][ks], bv[ni][ks], acc[mi][ni], 0, 0, 0);
    };

    STAGE(0, 0);
    __syncthreads();

    for (int t = 0; t < nk; t += 2) {
        if (t + 1 < nk) STAGE(1, (t + 1) * 64);
        compute(As[0], Bs[0]);
        __syncthreads();
        if (t + 1 < nk) {
            if (t + 2 < nk) STAGE(0, (t + 2) * 64);
            compute(As[1], Bs[1]);
            __syncthreads();
        }
    }
#undef STAGE

#pragma unroll
    for (int ni = 0; ni < 2; ++ni) {
        int col = colTile + wc * 32 + ni * 16 + frow;
        if (col < Ncols) {
            float bb = bp ? bp[col] : 0.f;
#pragma unroll
            for (int mi = 0; mi < 2; ++mi) {
                long rbase = rowTile + wr * 32 + mi * 16 + kgrp * 4;
#pragma unroll
                for (int r = 0; r < 4; ++r) {
                    float v = acc[mi][ni][r] + bb;
                    if (act == 1) v = fmaxf(v, 0.f);
                    st1(C + (rbase + r) * (long)ldc + col, v);
                }
            }
        }
    }
}

// ---------------------------------------------------------------------------
// MFMA flash attention per (dialogue, head). 256 thr = 4 waves.
// ---------------------------------------------------------------------------
__global__ __launch_bounds__(256) void attn_mfma_k(const bf16* __restrict__ qkv,
                                                   bf16* __restrict__ o)
{
    __shared__ bf16 Pb[128 * 136];   // 34.8 KB, A-layout P
    __shared__ bf16 Vt[64 * 136];    // 17.4 KB, V^T [dh][l]
    __shared__ float pm[128][2];     // per-row partial max (per wave-col)
    __shared__ float ps[128][2];     // per-row partial sum

    const int d = blockIdx.x, h = blockIdx.y;
    const long base = (long)d * L_SEQ;
    const int tid  = threadIdx.x;
    const int lane = tid & 63;
    const int wave = tid >> 6;
    const int frow = lane & 15;
    const int kgrp = lane >> 4;
    const int wr = wave >> 1;        // S row-half
    const int wc = wave & 1;         // S col-half
    const float SC = 0.125f;

    // ---- V[l][dh] -> Vt[dh][l] (one-time scalar transpose) -----------------
    {
        int l = tid >> 1, dh0 = (tid & 1) * 32;
        const bf16* vp = qkv + (base + l) * 1536 + 1024 + h * 64 + dh0;
        unsigned short* vt = (unsigned short*)Vt;
#pragma unroll
        for (int j = 0; j < 4; ++j) {
            short8 v = *(const short8*)(vp + j * 8);
#pragma unroll
            for (int jj = 0; jj < 8; ++jj)
                vt[(dh0 + j * 8 + jj) * 136 + l] = (unsigned short)v[jj];
        }
    }

    // ---- Q,K fragments direct from global (no reuse -> no LDS) -------------
    short8 aq[4][2], bk[4][2];
#pragma unroll
    for (int mi = 0; mi < 4; ++mi) {
        long row = base + wr * 64 + mi * 16 + frow;
#pragma unroll
        for (int ks = 0; ks < 2; ++ks)
            aq[mi][ks] = *(const short8*)(qkv + row * 1536 + h * 64 + ks * 32 + kgrp * 8);
    }
#pragma unroll
    for (int ni = 0; ni < 4; ++ni) {
        long row = base + wc * 64 + ni * 16 + frow;
#pragma unroll
        for (int ks = 0; ks < 2; ++ks)
            bk[ni][ks] = *(const short8*)(qkv + row * 1536 + 512 + h * 64 + ks * 32 + kgrp * 8);
    }

    // ---- S = Q @ K^T (64x64 per wave) --------------------------------------
    f32x4 acc[4][4];
#pragma unroll
    for (int i = 0; i < 4; ++i)
#pragma unroll
        for (int j = 0; j < 4; ++j) acc[i][j] = (f32x4){0.f, 0.f, 0.f, 0.f};
#pragma unroll
    for (int ks = 0; ks < 2; ++ks)
#pragma unroll
        for (int mi = 0; mi < 4; ++mi)
#pragma unroll
            for (int ni = 0; ni < 4; ++ni)
                acc[mi][ni] = __builtin_amdgcn_mfma_f32_16x16x32_bf16(
                    aq[mi][ks], bk[ni][ks], acc[mi][ni], 0, 0, 0);

    // ---- per-wave row partials ---------------------------------------------
#pragma unroll
    for (int mi = 0; mi < 4; ++mi) {
#pragma unroll
        for (int r = 0; r < 4; ++r) {
            float mv = -1e30f;
#pragma unroll
            for (int ni = 0; ni < 4; ++ni) mv = fmaxf(mv, acc[mi][ni][r] * SC);
#pragma unroll
            for (int off = 1; off < 16; off <<= 1)
                mv = fmaxf(mv, __shfl_xor(mv, off, 64));
            float sv = 0.f;
#pragma unroll
            for (int ni = 0; ni < 4; ++ni) sv += __expf(acc[mi][ni][r] * SC - mv);
#pragma unroll
            for (int off = 1; off < 16; off <<= 1)
                sv += __shfl_xor(sv, off, 64);
            if (frow == 0) {
                int row = wr * 64 + mi * 16 + kgrp * 4 + r;
                pm[row][wc] = mv;
                ps[row][wc] = sv;
            }
        }
    }
    __syncthreads();

    // ---- merge halves, write P (bf16, A-layout) ----------------------------
    unsigned short* pb = (unsigned short*)Pb;
#pragma unroll
    for (int mi = 0; mi < 4; ++mi) {
#pragma unroll
        for (int r = 0; r < 4; ++r) {
            int row = wr * 64 + mi * 16 + kgrp * 4 + r;
            float m0 = pm[row][0], m1 = pm[row][1];
            float M = fmaxf(m0, m1);
            float Ssum = ps[row][0] * __expf(m0 - M) + ps[row][1] * __expf(m1 - M);
            float inv = 1.f / Ssum;
#pragma unroll
            for (int ni = 0; ni < 4; ++ni) {
                int col = wc * 64 + ni * 16 + frow;
                float p = __expf(acc[mi][ni][r] * SC - M) * inv;
                pb[row * 136 + col] = fconv(p);
            }
        }
    }
    __syncthreads();

    // ---- O = P @ V ----------------------------------------------------------
    f32x4 acc2[2][4];
#pragma unroll
    for (int i = 0; i < 2; ++i)
#pragma unroll
        for (int j = 0; j < 4; ++j) acc2[i][j] = (f32x4){0.f, 0.f, 0.f, 0.f};
#pragma unroll
    for (int ks = 0; ks < 4; ++ks) {
        short8 ap[2], bv[4];
#pragma unroll
        for (int mi = 0; mi < 2; ++mi)
            ap[mi] = *(const short8*)(Pb + (wave * 32 + mi * 16 + frow) * 136 + ks * 32 + kgrp * 8);
#pragma unroll
        for (int ni = 0; ni < 4; ++ni)
            bv[ni] = *(const short8*)(Vt + (ni * 16 + frow) * 136 + ks * 32 + kgrp * 8);
#pragma unroll
        for (int mi = 0; mi < 2; ++mi)
#pragma unroll
            for (int ni = 0; ni < 4; ++ni)
                acc2[mi][ni] = __builtin_amdgcn_mfma_f32_16x16x32_bf16(
                    ap[mi], bv[ni], acc2[mi][ni], 0, 0, 0);
    }
#pragma unroll
    for (int mi = 0; mi < 2; ++mi) {
#pragma unroll
        for (int ni = 0; ni < 4; ++ni) {
            int col = ni * 16 + frow;
            long rowb = wave * 32 + mi * 16 + kgrp * 4;
#pragma unroll
            for (int r = 0; r < 4; ++r)
                st1(o + (base + rowb + r) * 512 + h * 64 + col, acc2[mi][ni][r]);
        }
    }
}

// ---------------------------------------------------------------------------
// Classifier head: out[N,7] = A[N,768] @ W[768,7] + bias. Wave per row.
// ---------------------------------------------------------------------------
__global__ __launch_bounds__(256) void head7_k(
    const bf16* __restrict__ A, const float* __restrict__ W,
    const float* __restrict__ bias, float* __restrict__ out)
{
    const int wave = threadIdx.x >> 6, lane = threadIdx.x & 63;
    const long row = blockIdx.x * 4 + wave;
    const bf16* a = A + row * 768;
    float acc[7];
#pragma unroll
    for (int j = 0; j < 7; ++j) acc[j] = 0.f;
#pragma unroll
    for (int i = 0; i < 12; ++i) {
        int k = lane + i * 64;
        float av = ld1(a + k);
        const float* w = W + k * 7;
#pragma unroll
        for (int j = 0; j < 7; ++j) acc[j] = fmaf(av, w[j], acc[j]);
    }
#pragma unroll
    for (int j = 0; j < 7; ++j)
#pragma unroll
        for (int o = 32; o > 0; o >>= 1) acc[j] += __shfl_down(acc[j], o, 64);
    if (lane == 0) {
#pragma unroll
        for (int j = 0; j < 7; ++j) out[row * 7 + j] = acc[j] + bias[j];
    }
}

// ---------------------------------------------------------------------------
// xcat: vectorized x4 (4-aligned quads never straddle source regions).
// ---------------------------------------------------------------------------
__global__ void xcat_k(const float* __restrict__ x, const float* __restrict__ spk_emb,
                       const int* __restrict__ sidx, bf16* __restrict__ out, int n_quads)
{
    int q = blockIdx.x * 256 + threadIdx.x;
    if (q >= n_quads) return;
    int i = q * 4;
    int n = i / 576;
    int c = i - n * 576;
    const float* sp = (c < 512) ? (x + (long)n * 512 + c)
                                : (spk_emb + (long)sidx[n] * 64 + (c - 512));
    float4 v = *(const float4*)sp;
    ushort4 u;
    u.x = fconv(v.x); u.y = fconv(v.y); u.z = fconv(v.z); u.w = fconv(v.w);
    *(ushort4*)(out + i) = u;
}

// ---------------------------------------------------------------------------
// add_ln: pair-loads; residual r is bf16.
// ---------------------------------------------------------------------------
__global__ __launch_bounds__(256) void add_ln_k(bf16* __restrict__ h, const bf16* __restrict__ r,
                                                const float* __restrict__ g, const float* __restrict__ b)
{
    const int row = blockIdx.x;
    const int tid = threadIdx.x;
    const long base = (long)row * 512 + tid * 2;
    ushort2 hu = *(const ushort2*)(h + base);
    ushort2 ru = *(const ushort2*)(r + base);
    float x0 = bconv(hu.x) + bconv(ru.x);
    float x1 = bconv(hu.y) + bconv(ru.y);
    float s = x0 + x1;
    float q = x0 * x0 + x1 * x1;
#pragma unroll
    for (int o = 32; o > 0; o >>= 1) { s += __shfl_down(s, o, 64); q += __shfl_down(q, o, 64); }
    __shared__ float ls[4], lq[4];
    if ((tid & 63) == 0) { ls[tid >> 6] = s; lq[tid >> 6] = q; }
    __syncthreads();
    float S = ls[0] + ls[1] + ls[2] + ls[3];
    float Q = lq[0] + lq[1] + lq[2] + lq[3];
    float mu = S * (1.f / 512.f);
    float var = Q * (1.f / 512.f) - mu * mu;
    float inv = rsqrtf(fmaxf(var, 0.f) + 1e-5f);
    float2 gv = *(const float2*)(g + tid * 2);
    float2 bv = *(const float2*)(b + tid * 2);
    ushort2 o2;
    o2.x = fconv((x0 - mu) * inv * gv.x + bv.x);
    o2.y = fconv((x1 - mu) * inv * gv.y + bv.y);
    *(ushort2*)(h + base) = o2;
}

__global__ __launch_bounds__(256) void skip_ln_relu_k(
    const float* __restrict__ outp, const bf16* __restrict__ curp, bf16* __restrict__ dst,
    const float* __restrict__ gskip, const float* __restrict__ g, const float* __restrict__ b)
{
    const int row = blockIdx.x;
    const int tid = threadIdx.x;
    const float beta = 1.f / (1.f + __expf(-gskip[0]));
    const long base = (long)row * 512 + tid * 2;
    float2 ov = *(const float2*)(outp + base);
    ushort2 cu = *(const ushort2*)(curp + base);
    float x0 = beta * ov.x + (1.f - beta) * bconv(cu.x);
    float x1 = beta * ov.y + (1.f - beta) * bconv(cu.y);
    float s = x0 + x1;
    float q = x0 * x0 + x1 * x1;
#pragma unroll
    for (int o = 32; o > 0; o >>= 1) { s += __shfl_down(s, o, 64); q += __shfl_down(q, o, 64); }
    __shared__ float ls[4], lq[4];
    if ((tid & 63) == 0) { ls[tid >> 6] = s; lq[tid >> 6] = q; }
    __syncthreads();
    float S = ls[0] + ls[1] + ls[2] + ls[3];
    float Q = lq[0] + lq[1] + lq[2] + lq[3];
    float mu = S * (1.f / 512.f);
    float var = Q * (1.f / 512.f) - mu * mu;
    float inv = rsqrtf(fmaxf(var, 0.f) + 1e-5f);
    float2 gv = *(const float2*)(g + tid * 2);
    float2 bv = *(const float2*)(b + tid * 2);
    ushort2 o2;
    o2.x = fconv(fmaxf((x0 - mu) * inv * gv.x + bv.x, 0.f));
    o2.y = fconv(fmaxf((x1 - mu) * inv * gv.y + bv.y, 0.f));
    *(ushort2*)(dst + base) = o2;
}

// ---------------------------------------------------------------------------
// Edge logits, CSR(dst)-ordered, XCD-swizzled blocks: each XCD gets a
// contiguous p-chunk -> contiguous dst range -> Q reads are XCD-local
// (no 8x L2 duplication of the Q table). kj gather stays random.
// ---------------------------------------------------------------------------
__global__ void edge_logit2_k(float* __restrict__ lg2, const bf16* __restrict__ qq,
                              const bf16* __restrict__ kj0, const bf16* __restrict__ kj1,
                              const int* __restrict__ ei, const int* __restrict__ ids,
                              const float* __restrict__ prel0, const float* __restrict__ prel1,
                              int r0, int r1)
{
    int blk = xcd_swz(blockIdx.x, gridDim.x);
    int tid = blk * 256 + threadIdx.x;
    int p = tid >> 3;                  // position within group, < 2*E_EDGES
    int h = tid & 7;
    int idx = ids[p];
    int gi = idx >> 15, e = idx & 32767;
    int r = gi ? r1 : r0;
    int dst = ei[((long)r * 2 + 1) * E_EDGES + e];
    int src = ei[((long)r * 2 + 0) * E_EDGES + e];
    const bf16* qp = qq + (long)dst * 512 + h * 64;
    const bf16* kp = (gi ? kj1 : kj0) + (long)src * 512 + h * 64;
    float acc = 0.f;
#pragma unroll
    for (int i = 0; i < 64; i += 4) {
        float4 a = ld4(qp + i);
        float4 c = ld4(kp + i);
        acc = fmaf(a.x, c.x, acc); acc = fmaf(a.y, c.y, acc);
        acc = fmaf(a.z, c.z, acc); acc = fmaf(a.w, c.w, acc);
    }
    lg2[(long)p * 8 + h] = acc * (gi ? prel1 : prel0)[h] * 0.125f;
}

// ---------------------------------------------------------------------------
// CSR build over dst: per dst-type group g (3 groups, 2 edge types each,
// 65536 edges -> 8192 dst nodes). ids pack: (gi<<15) | e.
// ---------------------------------------------------------------------------
__global__ void csr_zero_k(int* __restrict__ off, int* __restrict__ cur)
{
    int i = blockIdx.x * 256 + threadIdx.x;
    if (i < 3 * 8193) off[i] = 0;
    if (i < 3 * 8192) cur[i] = 0;
}

__global__ void csr_count_k(const int* __restrict__ ei, int* __restrict__ off)
{
    int tid = blockIdx.x * 256 + threadIdx.x;       // 3*2*E threads
    int g   = tid >> 16;                             // / 65536
    int rem = tid & 65535;
    int gi  = rem >> 15;
    int e   = rem & (E_EDGES - 1);
    const int GR[6] = {1, 3, 0, 5, 2, 4};
    int r   = GR[g * 2 + gi];
    int dst = ei[((long)r * 2 + 1) * E_EDGES + e];
    atomicAdd(&off[g * 8193 + dst + 1], 1);
}

__global__ __launch_bounds__(256) void csr_scan_k(int* __restrict__ off, int* __restrict__ cur)
{
    const int g = blockIdx.x, t = threadIdx.x;
    int* o = off + g * 8193;
    int v[32];
    int s = 0;
#pragma unroll
    for (int j = 0; j < 32; ++j) { v[j] = o[t * 32 + j + 1]; s += v[j]; }
    __shared__ int ps[256];
    ps[t] = s;
    __syncthreads();
    for (int d = 1; d < 256; d <<= 1) {
        int x = 0;
        if (t >= d) x = ps[t - d];
        __syncthreads();
        if (t >= d) ps[t] += x;
        __syncthreads();
    }
    int run = (t ? ps[t - 1] : 0);
#pragma unroll
    for (int j = 0; j < 32; ++j) {
        cur[g * 8192 + t * 32 + j] = run;   // exclusive prefix = fill cursor
        run += v[j];
        o[t * 32 + j + 1] = run;            // inclusive -> off[d+1]
    }
}

__global__ void csr_fill_k(const int* __restrict__ ei, int* __restrict__ cur,
                           int* __restrict__ ids)
{
    int tid = blockIdx.x * 256 + threadIdx.x;
    int g   = tid >> 16;
    int rem = tid & 65535;
    int gi  = rem >> 15;
    int e   = rem & (E_EDGES - 1);
    const int GR[6] = {1, 3, 0, 5, 2, 4};
    int r   = GR[g * 2 + gi];
    int dst = ei[((long)r * 2 + 1) * E_EDGES + e];
    int p = atomicAdd(&cur[g * 8192 + dst], 1);
    ids[g * 65536 + p] = (gi << 15) | e;
}

// ---------------------------------------------------------------------------
// Fused HGT aggregation: one block per dst node (XCD-swizzled -> contiguous
// node chunks per XCD); online segment softmax + alpha-weighted gather of
// mj[src] + GELU. No global atomics. Logits arrive dst-sorted (seq reads).
// ---------------------------------------------------------------------------
__global__ __launch_bounds__(256) void hgt_gather_k(
    const float* __restrict__ lg2, const int* __restrict__ ei,
    const int* __restrict__ off, const int* __restrict__ ids,
    const bf16* __restrict__ vt0, const bf16* __restrict__ vt1,
    bf16* __restrict__ aout, int r0, int r1)
{
    const int n = xcd_swz(blockIdx.x, gridDim.x);
    const int tid = threadIdx.x;
    const int beg = off[n], end = off[n + 1];

    __shared__ int   sh_idx[256];
    __shared__ float sh_al[256 * 8];    // logits, then unnormalized alphas
    __shared__ float pm[64];
    __shared__ float mrun[8], srun[8], resc[8];

    if (tid < 8) { mrun[tid] = -1e30f; srun[tid] = 0.f; }
    const int c0 = tid * 2;             // two consecutive channels, same head
    const int h  = tid >> 5;
    float a0 = 0.f, a1 = 0.f;
    __syncthreads();

    for (int t0 = beg; t0 < end; t0 += 256) {
        const int cnt = min(256, end - t0);
        if (tid < cnt) sh_idx[tid] = ids[t0 + tid];
        __syncthreads();
        // stage logits for this tile (sequential, dst-sorted layout)
        {
            const float* lgp = lg2 + (long)t0 * 8;
            for (int i = tid; i < cnt * 8; i += 256)
                sh_al[i] = lgp[i];
        }
        __syncthreads();
        // tile max per head (8 slots x 8 heads)
        if (tid < 64) {
            int hh = tid & 7, sl = tid >> 3;
            float m = -1e30f;
            for (int i = sl; i < cnt; i += 8) m = fmaxf(m, sh_al[i * 8 + hh]);
            pm[tid] = m;
        }
        __syncthreads();
        if (tid < 8) {
            float m = pm[tid];
#pragma unroll
            for (int sl = 1; sl < 8; ++sl) m = fmaxf(m, pm[sl * 8 + tid]);
            float nm = fmaxf(mrun[tid], m);
            resc[tid] = __expf(mrun[tid] - nm);
            mrun[tid] = nm;
        }
        __syncthreads();
        // rescale accumulators; unnormalized alphas in place
        float rs = resc[h];
        a0 *= rs; a1 *= rs;
        for (int i = tid; i < cnt * 8; i += 256)
            sh_al[i] = __expf(sh_al[i] - mrun[i & 7]);
        __syncthreads();
        // tile sum per head
        if (tid < 64) {
            int hh = tid & 7, sl = tid >> 3;
            float s = 0.f;
            for (int i = sl; i < cnt; i += 8) s += sh_al[i * 8 + hh];
            pm[tid] = s;
        }
        __syncthreads();
        if (tid < 8) {
            float s = 0.f;
#pragma unroll
            for (int sl = 0; sl < 8; ++sl) s += pm[sl * 8 + tid];
            srun[tid] = srun[tid] * resc[tid] + s;
        }
        // accumulate alpha * mj[src] (coalesced 4B/lane rows of mj)
        for (int i = 0; i < cnt; ++i) {
            int idx = sh_idx[i];
            int gi = idx >> 15, e = idx & 32767;
            int r = gi ? r1 : r0;
            float al = sh_al[i * 8 + h];
            int src = ei[((long)r * 2) * E_EDGES + e];
            const bf16* v = (gi ? vt1 : vt0) + (long)src * 512 + c0;
            ushort2 u = *(const ushort2*)v;
            a0 = fmaf(al, bconv(u.x), a0);
            a1 = fmaf(al, bconv(u.y), a1);
        }
        __syncthreads();
    }
    float iv = 1.f / (srun[h] + 1e-9f);
    a0 *= iv; a1 *= iv;
    // fused GELU (tanh approx), bf16 store
    float t0v = tanhf(0.79788456080286535588f * (a0 + 0.044715f * a0 * a0 * a0));
    float t1v = tanhf(0.79788456080286535588f * (a1 + 0.044715f * a1 * a1 * a1));
    unsigned short o0 = fconv(0.5f * a0 * (1.f + t0v));
    unsigned short o1 = fconv(0.5f * a1 * (1.f + t1v));
    *(ushort2*)(aout + (long)n * 512 + c0) = make_ushort2(o0, o1);
}

// ---------------------------------------------------------------------------
// concat3: vectorized x8 (512-boundaries are 8-aligned; bit-identical).
// ---------------------------------------------------------------------------
__global__ void concat3_k(const bf16* __restrict__ a, const bf16* __restrict__ b,
                          const bf16* __restrict__ c, bf16* __restrict__ out, int n_oct)
{
    int q = blockIdx.x * 256 + threadIdx.x;
    if (q >= n_oct) return;
    int i = q * 8;
    int n = i / 1536;
    int cc = i - n * 1536;
    const bf16* sp = (cc < 512) ? a : (cc < 1024 ? b : c);
    *(short8*)(out + i) = *(const short8*)(sp + (long)n * 512 + (cc & 511));
}

// ---------------------------------------------------------------------------
static inline void convT(hipStream_t st, const float* in, bf16* out, int K, int N, int z)
{
    dim3 g(N / 32, K / 32, z), b(32, 8);
    transpose_k<<<g, b, 0, st>>>(in, out, K, N);
}
static inline void mgemm(hipStream_t st, const bf16* A, const bf16* Bt, const float* bias,
                         bf16* C, int M, int K, int Ncols, int lda, int ldb, int ldc,
                         long sA, long sB, long sC, long sBias, int z, int act)
{
    dim3 g((Ncols + 63) / 64, M / 64, z);
    mgemm_k<bf16><<<g, 256, 0, st>>>(A, Bt, bias, C, M, K, Ncols, lda, ldb, ldc,
                                     sA, sB, sC, sBias, act);
}
static inline void mgemm_f(hipStream_t st, const bf16* A, const bf16* Bt, const float* bias,
                           float* C, int M, int K, int Ncols, int lda, int ldb, int ldc, int act)
{
    dim3 g((Ncols + 63) / 64, M / 64, 1);
    mgemm_k<float><<<g, 256, 0, st>>>(A, Bt, bias, C, M, K, Ncols, lda, ldb, ldc,
                                      0, 0, 0, 0, act);
}

extern "C" void kernel_launch(void* const* d_in, const int* in_sizes, int n_in,
                              void* d_out, int out_size, void* d_ws, size_t ws_size,
                              hipStream_t stream)
{
    const float* x_audio = (const float*)d_in[0];
    const float* x_text  = (const float*)d_in[1];
    const float* x_video = (const float*)d_in[2];
    const float* spk_emb = (const float*)d_in[3];
    const float* proj_w  = (const float*)d_in[4];
    const float* proj_b  = (const float*)d_in[5];
    const float* t_qkv_w = (const float*)d_in[6];
    const float* t_qkv_b = (const float*)d_in[7];
    const float* t_out_w = (const float*)d_in[8];
    const float* t_out_b = (const float*)d_in[9];
    const float* t_ff1_w = (const float*)d_in[10];
    const float* t_ff1_b = (const float*)d_in[11];
    const float* t_ff2_w = (const float*)d_in[12];
    const float* t_ff2_b = (const float*)d_in[13];
    const float* t_ln1_g = (const float*)d_in[14];
    const float* t_ln1_b = (const float*)d_in[15];
    const float* t_ln2_g = (const float*)d_in[16];
    const float* t_ln2_b = (const float*)d_in[17];
    const float* g_k_w   = (const float*)d_in[18];
    const float* g_k_b   = (const float*)d_in[19];
    const float* g_q_w   = (const float*)d_in[20];
    const float* g_q_b   = (const float*)d_in[21];
    const float* g_v_w   = (const float*)d_in[22];
    const float* g_v_b   = (const float*)d_in[23];
    const float* g_a_w   = (const float*)d_in[24];
    const float* g_a_b   = (const float*)d_in[25];
    const float* g_skip  = (const float*)d_in[26];
    const float* g_arel  = (const float*)d_in[27];
    const float* g_mrel  = (const float*)d_in[28];
    const float* g_prel  = (const float*)d_in[29];
    const float* g_ln_g  = (const float*)d_in[30];
    const float* g_ln_b  = (const float*)d_in[31];
    const float* c1_w    = (const float*)d_in[32];
    const float* c1_b    = (const float*)d_in[33];
    const float* c2_w    = (const float*)d_in[34];
    const float* c2_b    = (const float*)d_in[35];
    const int* speaker_idx = (const int*)d_in[36];
    const int* edge_index  = (const int*)d_in[38];

    const int N = N_NODES;
    const long NH = (long)N_NODES * H_DIM;

    // ---- bf16-transposed weight region (~56 MB) ----------------------------
    bf16* Wbf = (bf16*)d_ws;
    long off = 0;
    bf16* projT = Wbf + off; off += 3L * 512 * 576;
    bf16* qkvT  = Wbf + off; off += 6L * 1536 * 512;
    bf16* outT  = Wbf + off; off += 6L * 512 * 512;
    bf16* ff1T  = Wbf + off; off += 6L * 2048 * 512;
    bf16* ff2T  = Wbf + off; off += 6L * 512 * 2048;
    bf16* gkT   = Wbf + off; off += 6L * 512 * 512;
    bf16* gqT   = Wbf + off; off += 6L * 512 * 512;
    bf16* gvT   = Wbf + off; off += 6L * 512 * 512;
    bf16* gaT   = Wbf + off; off += 6L * 512 * 512;
    bf16* arelT = Wbf + off; off += 96L * 64 * 64;
    bf16* mrelT = Wbf + off; off += 96L * 64 * 64;
    bf16* c1T   = Wbf + off; off += 768L * 1536;
    off += 4096;  // slack

    // ---- activation workspace (unchanged footprint) ------------------------
    bf16* cur0  = Wbf + off;
    bf16* Kbuf  = cur0 + 3 * NH;
    bf16* QVbuf = Kbuf + 3 * NH;
    bf16* S     = QVbuf + 3 * NH;          // N*2048 scratch
    bf16* aux   = S + (long)N * 2048;      // 2*NH
    bf16* aux2  = aux + NH;

    bf16* xin   = S;
    bf16* qkvb  = S;
    bf16* attno = S + (long)N * 1536;
    bf16* outp  = S;
    bf16* ffb   = S;
    float* agg   = (float*)S;                               // 16.8 MB
    float* lgbuf = agg + NH;                                // 6.3 MB dst-sorted logits
    int* csr_off = (int*)(lgbuf + 3L * 2 * E_EDGES * 8);    // 3 x 8193
    int* csr_cur = csr_off + 3 * 8193;                      // 3 x 8192
    int* csr_ids = csr_cur + 3 * 8192;                      // 3 x 65536
    bf16* aout   = (bf16*)(csr_ids + 3 * 65536);            // 8.4 MB

    static const int META_S[6] = {0, 1, 0, 2, 1, 2};
    static const int GROUPS[3][2] = {{1, 3}, {0, 5}, {2, 4}};
    const float* xs[3] = {x_audio, x_text, x_video};

    // ---------------- Weight pre-pass ---------------------------------------
    convT(stream, proj_w,  projT, 576, 512, 3);
    convT(stream, t_qkv_w, qkvT,  512, 1536, 6);
    convT(stream, t_out_w, outT,  512, 512, 6);
    convT(stream, t_ff1_w, ff1T,  512, 2048, 6);
    convT(stream, t_ff2_w, ff2T,  2048, 512, 6);
    convT(stream, g_k_w,   gkT,   512, 512, 6);
    convT(stream, g_q_w,   gqT,   512, 512, 6);
    convT(stream, g_v_w,   gvT,   512, 512, 6);
    convT(stream, g_a_w,   gaT,   512, 512, 6);
    convT(stream, g_arel,  arelT, 64, 64, 96);
    convT(stream, g_mrel,  mrelT, 64, 64, 96);
    convT(stream, c1_w,    c1T,   1536, 768, 1);

    // ---------------- Stage 1+2: projection + transformer encoder ----------
    for (int t = 0; t < 3; ++t) {
        bf16* h = cur0 + (long)t * NH;
        xcat_k<<<(N * 576 / 4) / 256, 256, 0, stream>>>(xs[t], spk_emb, speaker_idx,
                                                        xin, N * 576 / 4);
        mgemm(stream, xin, projT + (long)t * 512 * 576, proj_b + (long)t * 512, h,
              N, 576, 512, 576, 576, 512, 0, 0, 0, 0, 1, 0);
        for (int l = 0; l < 2; ++l) {
            long wi = (long)t * 2 + l;
            mgemm(stream, h, qkvT + wi * 1536 * 512, t_qkv_b + wi * 1536, qkvb,
                  N, 512, 1536, 512, 512, 1536, 0, 0, 0, 0, 1, 0);
            attn_mfma_k<<<dim3(D_DLG, N_HEADS), 256, 0, stream>>>(qkvb, attno);
            mgemm(stream, attno, outT + wi * 512 * 512, t_out_b + wi * 512, outp,
                  N, 512, 512, 512, 512, 512, 0, 0, 0, 0, 1, 0);
            add_ln_k<<<N, 256, 0, stream>>>(h, outp, t_ln1_g + wi * 512, t_ln1_b + wi * 512);
            mgemm(stream, h, ff1T + wi * 2048 * 512, t_ff1_b + wi * 2048, ffb,
                  N, 512, 2048, 512, 512, 2048, 0, 0, 0, 0, 1, 1);
            mgemm(stream, ffb, ff2T + wi * 512 * 2048, t_ff2_b + wi * 512, aux,
                  N, 2048, 512, 2048, 2048, 512, 0, 0, 0, 0, 1, 0);
            add_ln_k<<<N, 256, 0, stream>>>(h, aux, t_ln2_g + wi * 512, t_ln2_b + wi * 512);
        }
    }

    // ---------------- CSR build (once; edge_index is layer-invariant) -------
    csr_zero_k<<<(3 * 8193 + 255) / 256, 256, 0, stream>>>(csr_off, csr_cur);
    csr_count_k<<<(3 * 2 * E_EDGES) / 256, 256, 0, stream>>>(edge_index, csr_off);
    csr_scan_k<<<3, 256, 0, stream>>>(csr_off, csr_cur);
    csr_fill_k<<<(3 * 2 * E_EDGES) / 256, 256, 0, stream>>>(edge_index, csr_cur, csr_ids);

    // ---------------- Stage 3: HGT layers ----------------------------------
    bf16* cur = cur0;
    for (int l = 0; l < 2; ++l) {
        bf16* Kr  = (l == 0) ? Kbuf : cur0;
        bf16* QVr = QVbuf;
        bf16* nxt = Kr;
        // z-batched K and Q projections over the 3 node types
        mgemm(stream, cur, gkT + (long)l * 3 * 512 * 512, g_k_b + (long)l * 3 * 512, Kr,
              N, 512, 512, 512, 512, 512, NH, 512L * 512, NH, 512, 3, 0);
        mgemm(stream, cur, gqT + (long)l * 3 * 512 * 512, g_q_b + (long)l * 3 * 512, QVr,
              N, 512, 512, 512, 512, 512, NH, 512L * 512, NH, 512, 3, 0);
        // per dst-group: kj for both incoming edge types, then CSR-ordered logits
        for (int t = 0; t < 3; ++t) {
            int r0 = GROUPS[t][0], r1 = GROUPS[t][1];
            mgemm(stream, Kr + (long)META_S[r0] * NH,
                  arelT + ((long)l * 6 + r0) * 8 * 64 * 64, nullptr, aux,
                  N, 64, 64, 512, 64, 512, 64, 64 * 64, 64, 0, 8, 0);
            mgemm(stream, Kr + (long)META_S[r1] * NH,
                  arelT + ((long)l * 6 + r1) * 8 * 64 * 64, nullptr, aux2,
                  N, 64, 64, 512, 64, 512, 64, 64 * 64, 64, 0, 8, 0);
            edge_logit2_k<<<(2 * E_EDGES * 8) / 256, 256, 0, stream>>>(
                lgbuf + (long)t * 2 * E_EDGES * 8, QVr + (long)t * NH, aux, aux2,
                edge_index, csr_ids + t * 65536,
                g_prel + ((long)l * 6 + r0) * 8, g_prel + ((long)l * 6 + r1) * 8, r0, r1);
        }
        // z-batched V projection (after edge logits consumed Q from QVr)
        mgemm(stream, cur, gvT + (long)l * 3 * 512 * 512, g_v_b + (long)l * 3 * 512, QVr,
              N, 512, 512, 512, 512, 512, NH, 512L * 512, NH, 512, 3, 0);
        for (int t = 0; t < 3; ++t) {
            int r0 = GROUPS[t][0], r1 = GROUPS[t][1];
            // mj = V @ mrel for the two incoming edge types
            mgemm(stream, QVr + (long)META_S[r0] * NH,
                  mrelT + ((long)l * 6 + r0) * 8 * 64 * 64, nullptr, aux,
                  N, 64, 64, 512, 64, 512, 64, 64 * 64, 64, 0, 8, 0);
            mgemm(stream, QVr + (long)META_S[r1] * NH,
                  mrelT + ((long)l * 6 + r1) * 8 * 64 * 64, nullptr, aux2,
                  N, 64, 64, 512, 64, 512, 64, 64 * 64, 64, 0, 8, 0);
            // fused softmax + gather + GELU (no atomics)
            hgt_gather_k<<<N, 256, 0, stream>>>(lgbuf + (long)t * 2 * E_EDGES * 8,
                                                edge_index,
                                                csr_off + t * 8193, csr_ids + t * 65536,
                                                aux, aux2, aout, r0, r1);
            long wi = (long)l * 3 + t;
            mgemm_f(stream, aout, gaT + wi * 512 * 512, g_a_b + wi * 512, agg,
                    N, 512, 512, 512, 512, 512, 0);
            skip_ln_relu_k<<<N, 256, 0, stream>>>(agg, cur + (long)t * NH, nxt + (long)t * NH,
                                                  g_skip + (long)l * 3 + t,
                                                  g_ln_g + wi * 512, g_ln_b + wi * 512);
        }
        cur = nxt;
    }

    // ---------------- Classifier (cur == cur0) ------------------------------
    bf16* ci = S;
    bf16* c1out = QVbuf;
    concat3_k<<<(N * 1536 / 8) / 256, 256, 0, stream>>>(cur, cur + NH, cur + 2 * NH,
                                                        ci, N * 1536 / 8);
    mgemm(stream, ci, c1T, c1_b, c1out, N, 1536, 768, 1536, 1536, 768, 0, 0, 0, 0, 1, 1);
    head7_k<<<N / 4, 256, 0, stream>>>(c1out, c2_w, c2_b, (float*)d_out);
}